// Round 1
// baseline (8925.185 us; speedup 1.0000x reference)
//
#include <hip/hip_runtime.h>

#define DIM 128
#define NITERS 4

typedef _Float16 f16x8 __attribute__((ext_vector_type(8)));
typedef _Float16 f16x4 __attribute__((ext_vector_type(4)));
typedef float f32x4 __attribute__((ext_vector_type(4)));

#define MFMA16(a, b, c) __builtin_amdgcn_mfma_f32_16x16x32_f16((a), (b), (c), 0, 0, 0)

__device__ __forceinline__ float sigmoidf_(float x) { return 1.f / (1.f + __expf(-x)); }
// tanh via exp; saturates correctly at +/-1 for large |x|
__device__ __forceinline__ float tanhf_(float x) { return 1.f - 2.f / (__expf(2.f * x) + 1.f); }

// Load an 8-wide fp16 fragment from 8 consecutive f32 (converts on the fly).
__device__ __forceinline__ f16x8 frag_from_f32(const float* __restrict__ p) {
    float4 a = *(const float4*)p;
    float4 b = *(const float4*)(p + 4);
    f16x8 r;
    r[0] = (_Float16)a.x; r[1] = (_Float16)a.y; r[2] = (_Float16)a.z; r[3] = (_Float16)a.w;
    r[4] = (_Float16)b.x; r[5] = (_Float16)b.y; r[6] = (_Float16)b.z; r[7] = (_Float16)b.w;
    return r;
}

__global__ void f32_to_f16_kernel(const float* __restrict__ in, _Float16* __restrict__ out, int n) {
    int i = blockIdx.x * 256 + threadIdx.x;
    if (i < n) out[i] = (_Float16)in[i];
}

// y = relu(x @ W1^T + b1) @ W2^T + b2 ; x f32 [M,128], W f16 [128,128] row-major ([n][k]), y f16 [M,128]
// block = 256 (4 waves), each wave owns 16 rows -> 64 rows/block
__global__ __launch_bounds__(256) void mlp_kernel(
    const float* __restrict__ X, const _Float16* __restrict__ W1, const float* __restrict__ B1,
    const _Float16* __restrict__ W2, const float* __restrict__ B2,
    _Float16* __restrict__ Y, int M)
{
    __shared__ _Float16 hbuf[4][16][DIM + 8];  // per-wave hidden tile, padded
    const int lane = threadIdx.x & 63;
    const int wave = threadIdx.x >> 6;
    const int m0 = blockIdx.x * 64 + wave * 16;
    if (m0 >= M) return;
    const int l15 = lane & 15;   // A: row, B: col, C/D: col
    const int kg  = lane >> 4;   // k-group

    f16x8 a[4];
    {
        const float* xp = X + (size_t)(m0 + l15) * DIM + kg * 8;
        #pragma unroll
        for (int kk = 0; kk < 4; ++kk) a[kk] = frag_from_f32(xp + kk * 32);
    }
    // stage 1: h = relu(x@W1^T + b1), write to LDS in row-major [row][k]
    for (int jt = 0; jt < 8; ++jt) {
        f32x4 acc = {0.f, 0.f, 0.f, 0.f};
        const _Float16* wp = W1 + (size_t)(jt * 16 + l15) * DIM + kg * 8;
        #pragma unroll
        for (int kk = 0; kk < 4; ++kk)
            acc = MFMA16(a[kk], *(const f16x8*)(wp + kk * 32), acc);
        float bias = B1[jt * 16 + l15];
        #pragma unroll
        for (int r = 0; r < 4; ++r) {
            float v = acc[r] + bias;
            hbuf[wave][kg * 4 + r][jt * 16 + l15] = (_Float16)(v > 0.f ? v : 0.f);
        }
    }
    // stage 2 (wave-private LDS; compiler orders ds ops): y = h@W2^T + b2
    f16x8 h[4];
    #pragma unroll
    for (int kk = 0; kk < 4; ++kk)
        h[kk] = *(const f16x8*)(&hbuf[wave][l15][kk * 32 + kg * 8]);
    for (int jt = 0; jt < 8; ++jt) {
        f32x4 acc = {0.f, 0.f, 0.f, 0.f};
        const _Float16* wp = W2 + (size_t)(jt * 16 + l15) * DIM + kg * 8;
        #pragma unroll
        for (int kk = 0; kk < 4; ++kk)
            acc = MFMA16(h[kk], *(const f16x8*)(wp + kk * 32), acc);
        float bias = B2[jt * 16 + l15];
        #pragma unroll
        for (int r = 0; r < 4; ++r)
            Y[(size_t)(m0 + kg * 4 + r) * DIM + jt * 16 + l15] = (_Float16)(acc[r] + bias);
    }
}

// edge scatter: aggr[dst[e]] += msg[src[e]] ; 32 threads/edge, 4 dims/thread
__global__ __launch_bounds__(256) void scatter_kernel(
    const _Float16* __restrict__ msg, const int* __restrict__ src, const int* __restrict__ dst,
    float* __restrict__ aggr, int n_edges)
{
    int tid = blockIdx.x * 256 + threadIdx.x;
    int e = tid >> 5;
    if (e >= n_edges) return;
    int dpart = (tid & 31) << 2;
    int s = src[e], d = dst[e];
    f16x4 v = *(const f16x4*)(msg + (size_t)s * DIM + dpart);
    float* ap = aggr + (size_t)d * DIM + dpart;
    atomicAdd(ap + 0, (float)v[0]);
    atomicAdd(ap + 1, (float)v[1]);
    atomicAdd(ap + 2, (float)v[2]);
    atomicAdd(ap + 3, (float)v[3]);
}

// GRU for clauses: h' = GRUCell(x=l2c_aggr, h) ; Wih,Whh f16 [384,128]
__global__ __launch_bounds__(256) void gru_c_kernel(
    const float* __restrict__ X, const float* __restrict__ H,
    const _Float16* __restrict__ Wih, const _Float16* __restrict__ Whh,
    const float* __restrict__ bih, const float* __restrict__ bhh,
    float* __restrict__ Hout, int M)
{
    const int lane = threadIdx.x & 63;
    const int wave = threadIdx.x >> 6;
    const int m0 = blockIdx.x * 64 + wave * 16;
    if (m0 >= M) return;
    const int l15 = lane & 15;
    const int kg  = lane >> 4;

    f16x8 xa[4], ha[4];
    {
        const float* xp = X + (size_t)(m0 + l15) * DIM + kg * 8;
        const float* hp = H + (size_t)(m0 + l15) * DIM + kg * 8;
        #pragma unroll
        for (int kk = 0; kk < 4; ++kk) {
            xa[kk] = frag_from_f32(xp + kk * 32);
            ha[kk] = frag_from_f32(hp + kk * 32);
        }
    }
    for (int jt = 0; jt < 8; ++jt) {
        const int j0 = jt * 16;
        f32x4 ar = {0,0,0,0}, az = {0,0,0,0}, agn = {0,0,0,0}, ahn = {0,0,0,0};
        const _Float16* wi = Wih + (size_t)(j0 + l15) * DIM + kg * 8;
        const _Float16* wh = Whh + (size_t)(j0 + l15) * DIM + kg * 8;
        #pragma unroll
        for (int kk = 0; kk < 4; ++kk) {
            const int o = kk * 32;
            ar  = MFMA16(xa[kk], *(const f16x8*)(wi + o), ar);
            az  = MFMA16(xa[kk], *(const f16x8*)(wi + 128 * DIM + o), az);
            agn = MFMA16(xa[kk], *(const f16x8*)(wi + 256 * DIM + o), agn);
            ar  = MFMA16(ha[kk], *(const f16x8*)(wh + o), ar);
            az  = MFMA16(ha[kk], *(const f16x8*)(wh + 128 * DIM + o), az);
            ahn = MFMA16(ha[kk], *(const f16x8*)(wh + 256 * DIM + o), ahn);
        }
        const int col = j0 + l15;
        float brc = bih[col] + bhh[col];
        float bzc = bih[128 + col] + bhh[128 + col];
        float bgn = bih[256 + col];
        float bhn = bhh[256 + col];
        #pragma unroll
        for (int r = 0; r < 4; ++r) {
            int m = m0 + kg * 4 + r;
            float rg = sigmoidf_(ar[r] + brc);
            float zg = sigmoidf_(az[r] + bzc);
            float ng = tanhf_(agn[r] + bgn + rg * (ahn[r] + bhn));
            float h = H[(size_t)m * DIM + col];
            Hout[(size_t)m * DIM + col] = (1.f - zg) * ng + zg * h;
        }
    }
}

// GRU for literals: x = concat(c2l_aggr[m], L[m^1]) (256-wide), h = L[m]
// Wih f16 [384,256], Whh f16 [384,128]
__global__ __launch_bounds__(256) void gru_l_kernel(
    const float* __restrict__ X, const float* __restrict__ L,
    const _Float16* __restrict__ Wih, const _Float16* __restrict__ Whh,
    const float* __restrict__ bih, const float* __restrict__ bhh,
    float* __restrict__ Lout, int M)
{
    const int lane = threadIdx.x & 63;
    const int wave = threadIdx.x >> 6;
    const int m0 = blockIdx.x * 64 + wave * 16;
    if (m0 >= M) return;
    const int l15 = lane & 15;
    const int kg  = lane >> 4;
    const int mrow = m0 + l15;

    f16x8 xa[4], xs[4], ha[4];
    {
        const float* xp = X + (size_t)mrow * DIM + kg * 8;
        const float* sp = L + (size_t)(mrow ^ 1) * DIM + kg * 8;  // negated-literal partner
        const float* hp = L + (size_t)mrow * DIM + kg * 8;
        #pragma unroll
        for (int kk = 0; kk < 4; ++kk) {
            xa[kk] = frag_from_f32(xp + kk * 32);
            xs[kk] = frag_from_f32(sp + kk * 32);
            ha[kk] = frag_from_f32(hp + kk * 32);
        }
    }
    for (int jt = 0; jt < 8; ++jt) {
        const int j0 = jt * 16;
        f32x4 ar = {0,0,0,0}, az = {0,0,0,0}, agn = {0,0,0,0}, ahn = {0,0,0,0};
        const _Float16* wi = Wih + (size_t)(j0 + l15) * 256 + kg * 8;
        const _Float16* wh = Whh + (size_t)(j0 + l15) * DIM + kg * 8;
        #pragma unroll
        for (int kk = 0; kk < 4; ++kk) {
            const int o = kk * 32;
            ar  = MFMA16(xa[kk], *(const f16x8*)(wi + o), ar);
            az  = MFMA16(xa[kk], *(const f16x8*)(wi + 128 * 256 + o), az);
            agn = MFMA16(xa[kk], *(const f16x8*)(wi + 256 * 256 + o), agn);
            ar  = MFMA16(xs[kk], *(const f16x8*)(wi + 128 + o), ar);
            az  = MFMA16(xs[kk], *(const f16x8*)(wi + 128 * 256 + 128 + o), az);
            agn = MFMA16(xs[kk], *(const f16x8*)(wi + 256 * 256 + 128 + o), agn);
            ar  = MFMA16(ha[kk], *(const f16x8*)(wh + o), ar);
            az  = MFMA16(ha[kk], *(const f16x8*)(wh + 128 * DIM + o), az);
            ahn = MFMA16(ha[kk], *(const f16x8*)(wh + 256 * DIM + o), ahn);
        }
        const int col = j0 + l15;
        float brc = bih[col] + bhh[col];
        float bzc = bih[128 + col] + bhh[128 + col];
        float bgn = bih[256 + col];
        float bhn = bhh[256 + col];
        #pragma unroll
        for (int r = 0; r < 4; ++r) {
            int m = m0 + kg * 4 + r;
            float rg = sigmoidf_(ar[r] + brc);
            float zg = sigmoidf_(az[r] + bzc);
            float ng = tanhf_(agn[r] + bgn + rg * (ahn[r] + bhn));
            float h = L[(size_t)m * DIM + col];
            Lout[(size_t)m * DIM + col] = (1.f - zg) * ng + zg * h;
        }
    }
}

extern "C" void kernel_launch(void* const* d_in, const int* in_sizes, int n_in,
                              void* d_out, int out_size, void* d_ws, size_t ws_size,
                              hipStream_t stream)
{
    const int*   l_edge = (const int*)d_in[2];
    const int*   c_edge = (const int*)d_in[3];
    const float* l_emb0 = (const float*)d_in[4];
    const float* c_emb0 = (const float*)d_in[5];
    const float* l2c_w1 = (const float*)d_in[6];
    const float* l2c_b1 = (const float*)d_in[7];
    const float* l2c_w2 = (const float*)d_in[8];
    const float* l2c_b2 = (const float*)d_in[9];
    const float* c2l_w1 = (const float*)d_in[10];
    const float* c2l_b1 = (const float*)d_in[11];
    const float* c2l_w2 = (const float*)d_in[12];
    const float* c2l_b2 = (const float*)d_in[13];
    const float* c_w_ih = (const float*)d_in[14];
    const float* c_w_hh = (const float*)d_in[15];
    const float* c_b_ih = (const float*)d_in[16];
    const float* c_b_hh = (const float*)d_in[17];
    const float* l_w_ih = (const float*)d_in[18];
    const float* l_w_hh = (const float*)d_in[19];
    const float* l_b_ih = (const float*)d_in[20];
    const float* l_b_hh = (const float*)d_in[21];

    const int n_edges = in_sizes[2];
    const int Lsz = in_sizes[4] / DIM;   // 80000
    const int Csz = in_sizes[5] / DIM;   // 160000

    float* OUT_L = (float*)d_out;                                  // (5, Lsz, 128)
    float* OUT_C = OUT_L + (size_t)(NITERS + 1) * Lsz * DIM;       // (5, Csz, 128)

    // workspace carve (~185 MB total)
    char* wsp = (char*)d_ws;
    auto carve = [&](size_t bytes) -> void* {
        void* p = (void*)wsp;
        wsp += (bytes + 255) & ~(size_t)255;
        return p;
    };
    _Float16* c_msg    = (_Float16*)carve((size_t)Csz * DIM * sizeof(_Float16));
    _Float16* l_msg    = (_Float16*)carve((size_t)Lsz * DIM * sizeof(_Float16));
    float*    l2c_aggr = (float*)   carve((size_t)Csz * DIM * sizeof(float));
    float*    c2l_aggr = (float*)   carve((size_t)Lsz * DIM * sizeof(float));
    _Float16* hw_l2c1 = (_Float16*)carve((size_t)DIM * DIM * 2);
    _Float16* hw_l2c2 = (_Float16*)carve((size_t)DIM * DIM * 2);
    _Float16* hw_c2l1 = (_Float16*)carve((size_t)DIM * DIM * 2);
    _Float16* hw_c2l2 = (_Float16*)carve((size_t)DIM * DIM * 2);
    _Float16* hw_cih  = (_Float16*)carve((size_t)3 * DIM * DIM * 2);
    _Float16* hw_chh  = (_Float16*)carve((size_t)3 * DIM * DIM * 2);
    _Float16* hw_lih  = (_Float16*)carve((size_t)3 * DIM * 2 * DIM * 2);
    _Float16* hw_lhh  = (_Float16*)carve((size_t)3 * DIM * DIM * 2);

    auto conv = [&](const float* s, _Float16* d, int n) {
        f32_to_f16_kernel<<<(n + 255) / 256, 256, 0, stream>>>(s, d, n);
    };
    conv(l2c_w1, hw_l2c1, DIM * DIM);
    conv(l2c_w2, hw_l2c2, DIM * DIM);
    conv(c2l_w1, hw_c2l1, DIM * DIM);
    conv(c2l_w2, hw_c2l2, DIM * DIM);
    conv(c_w_ih, hw_cih, 3 * DIM * DIM);
    conv(c_w_hh, hw_chh, 3 * DIM * DIM);
    conv(l_w_ih, hw_lih, 3 * DIM * 2 * DIM);
    conv(l_w_hh, hw_lhh, 3 * DIM * DIM);

    // initial slices
    hipMemcpyAsync(OUT_L, l_emb0, (size_t)Lsz * DIM * sizeof(float), hipMemcpyDeviceToDevice, stream);
    hipMemcpyAsync(OUT_C, c_emb0, (size_t)Csz * DIM * sizeof(float), hipMemcpyDeviceToDevice, stream);

    const int scat_blocks = (n_edges * 32 + 255) / 256;
    for (int t = 0; t < NITERS; ++t) {
        const float* Lt = OUT_L + (size_t)t * Lsz * DIM;
        const float* Ct = OUT_C + (size_t)t * Csz * DIM;
        float* Lt1 = OUT_L + (size_t)(t + 1) * Lsz * DIM;
        float* Ct1 = OUT_C + (size_t)(t + 1) * Csz * DIM;

        hipMemsetAsync(l2c_aggr, 0, (size_t)Csz * DIM * sizeof(float), stream);
        hipMemsetAsync(c2l_aggr, 0, (size_t)Lsz * DIM * sizeof(float), stream);

        mlp_kernel<<<(Lsz + 63) / 64, 256, 0, stream>>>(Lt, hw_l2c1, l2c_b1, hw_l2c2, l2c_b2, l_msg, Lsz);
        mlp_kernel<<<(Csz + 63) / 64, 256, 0, stream>>>(Ct, hw_c2l1, c2l_b1, hw_c2l2, c2l_b2, c_msg, Csz);
        scatter_kernel<<<scat_blocks, 256, 0, stream>>>(l_msg, l_edge, c_edge, l2c_aggr, n_edges);
        scatter_kernel<<<scat_blocks, 256, 0, stream>>>(c_msg, c_edge, l_edge, c2l_aggr, n_edges);
        gru_c_kernel<<<(Csz + 63) / 64, 256, 0, stream>>>(l2c_aggr, Ct, hw_cih, hw_chh, c_b_ih, c_b_hh, Ct1, Csz);
        gru_l_kernel<<<(Lsz + 63) / 64, 256, 0, stream>>>(c2l_aggr, Lt, hw_lih, hw_lhh, l_b_ih, l_b_hh, Lt1, Lsz);
    }
}

// Round 2
// 2869.144 us; speedup vs baseline: 3.1107x; 3.1107x over previous
//
#include <hip/hip_runtime.h>

#define DIM 128
#define NITERS 4

typedef _Float16 f16x8 __attribute__((ext_vector_type(8)));
typedef _Float16 f16x4 __attribute__((ext_vector_type(4)));
typedef _Float16 f16x2 __attribute__((ext_vector_type(2)));
typedef float f32x4 __attribute__((ext_vector_type(4)));

#define MFMA16(a, b, c) __builtin_amdgcn_mfma_f32_16x16x32_f16((a), (b), (c), 0, 0, 0)

__device__ __forceinline__ float sigmoidf_(float x) { return 1.f / (1.f + __expf(-x)); }
__device__ __forceinline__ float tanhf_(float x) { return 1.f - 2.f / (__expf(2.f * x) + 1.f); }

// Load an 8-wide fp16 fragment from 8 consecutive f32 (converts on the fly).
__device__ __forceinline__ f16x8 frag_from_f32(const float* __restrict__ p) {
    float4 a = *(const float4*)p;
    float4 b = *(const float4*)(p + 4);
    f16x8 r;
    r[0] = (_Float16)a.x; r[1] = (_Float16)a.y; r[2] = (_Float16)a.z; r[3] = (_Float16)a.w;
    r[4] = (_Float16)b.x; r[5] = (_Float16)b.y; r[6] = (_Float16)b.z; r[7] = (_Float16)b.w;
    return r;
}

__global__ void f32_to_f16_kernel(const float* __restrict__ in, _Float16* __restrict__ out, int n) {
    int i = blockIdx.x * 256 + threadIdx.x;
    if (i < n) out[i] = (_Float16)in[i];
}

// ---------------- CSR build (once per launch) ----------------

__global__ __launch_bounds__(256) void hist_kernel(const int* __restrict__ idx, int* __restrict__ deg, int n) {
    int i = blockIdx.x * 256 + threadIdx.x;
    if (i < n) atomicAdd(deg + idx[i], 1);
}

// phase 1: per-block (1024-elem) sums
__global__ __launch_bounds__(256) void scan_reduce(const int* __restrict__ deg, int* __restrict__ bsum, int n) {
    __shared__ int sh[256];
    const int t = threadIdx.x;
    const int base = blockIdx.x * 1024 + t * 4;
    int v = 0;
    #pragma unroll
    for (int k = 0; k < 4; ++k) { int i = base + k; if (i < n) v += deg[i]; }
    sh[t] = v; __syncthreads();
    for (int off = 128; off > 0; off >>= 1) {
        if (t < off) sh[t] += sh[t + off];
        __syncthreads();
    }
    if (t == 0) bsum[blockIdx.x] = sh[0];
}

// phase 2: exclusive scan of block sums (nb <= 256), single block
__global__ __launch_bounds__(256) void scan_blocksums(int* __restrict__ bsum, int nb) {
    __shared__ int sh[256];
    const int t = threadIdx.x;
    int v = (t < nb) ? bsum[t] : 0;
    sh[t] = v; __syncthreads();
    for (int off = 1; off < 256; off <<= 1) {
        int u = (t >= off) ? sh[t - off] : 0;
        __syncthreads();
        sh[t] += u;
        __syncthreads();
    }
    if (t < nb) bsum[t] = sh[t] - v;  // exclusive
}

// phase 3: write exclusive row starts
__global__ __launch_bounds__(256) void scan_write(const int* __restrict__ deg, const int* __restrict__ bsum,
                                                  int* __restrict__ rs, int n) {
    __shared__ int sh[256];
    const int t = threadIdx.x;
    const int base = blockIdx.x * 1024 + t * 4;
    int v[4], p[4], s = 0;
    #pragma unroll
    for (int k = 0; k < 4; ++k) {
        int i = base + k;
        v[k] = (i < n) ? deg[i] : 0;
        p[k] = s; s += v[k];
    }
    sh[t] = s; __syncthreads();
    for (int off = 1; off < 256; off <<= 1) {
        int u = (t >= off) ? sh[t - off] : 0;
        __syncthreads();
        sh[t] += u;
        __syncthreads();
    }
    int off0 = bsum[blockIdx.x] + (sh[t] - s);
    #pragma unroll
    for (int k = 0; k < 4; ++k) {
        int i = base + k;
        if (i < n) rs[i] = off0 + p[k];
    }
}

__global__ void set_int_kernel(int* p, int v) { *p = v; }

// fill: csr[rs[dst[e]] + slot] = src[e]
__global__ __launch_bounds__(256) void fill_kernel(const int* __restrict__ src, const int* __restrict__ dst,
                                                   const int* __restrict__ rs, int* __restrict__ cur,
                                                   int* __restrict__ csr, int n) {
    int e = blockIdx.x * 256 + threadIdx.x;
    if (e >= n) return;
    int d = dst[e];
    int slot = atomicAdd(cur + d, 1);
    csr[rs[d] + slot] = src[e];
}

// ---------------- pull-based aggregation ----------------
// one wave per destination row; lane owns 2 dims; sources broadcast via shfl
__global__ __launch_bounds__(256) void gather_kernel(const _Float16* __restrict__ msg,
                                                     const int* __restrict__ rs, const int* __restrict__ csr,
                                                     _Float16* __restrict__ aggr, int n_dst) {
    const int lane = threadIdx.x & 63;
    const int wave = threadIdx.x >> 6;
    const int d = blockIdx.x * 4 + wave;
    if (d >= n_dst) return;
    const int beg = rs[d], end = rs[d + 1];
    float ax = 0.f, ay = 0.f;
    for (int base = beg; base < end; base += 64) {
        int cnt = end - base; if (cnt > 64) cnt = 64;
        int sid = (lane < cnt) ? csr[base + lane] : 0;
        for (int j = 0; j < cnt; ++j) {
            int s = __shfl(sid, j);
            f16x2 v = *(const f16x2*)(msg + (size_t)s * DIM + lane * 2);
            ax += (float)v[0]; ay += (float)v[1];
        }
    }
    f16x2 o; o[0] = (_Float16)ax; o[1] = (_Float16)ay;
    *(f16x2*)(aggr + (size_t)d * DIM + lane * 2) = o;
}

// ---------------- MLP ----------------
// y = relu(x @ W1^T + b1) @ W2^T + b2 ; x f32 [M,128], W f16 [128,128] row-major, y f16 [M,128]
__global__ __launch_bounds__(256) void mlp_kernel(
    const float* __restrict__ X, const _Float16* __restrict__ W1, const float* __restrict__ B1,
    const _Float16* __restrict__ W2, const float* __restrict__ B2,
    _Float16* __restrict__ Y, int M)
{
    __shared__ _Float16 hbuf[4][16][DIM + 8];
    const int lane = threadIdx.x & 63;
    const int wave = threadIdx.x >> 6;
    const int m0 = blockIdx.x * 64 + wave * 16;
    if (m0 >= M) return;
    const int l15 = lane & 15;
    const int kg  = lane >> 4;

    f16x8 a[4];
    {
        const float* xp = X + (size_t)(m0 + l15) * DIM + kg * 8;
        #pragma unroll
        for (int kk = 0; kk < 4; ++kk) a[kk] = frag_from_f32(xp + kk * 32);
    }
    for (int jt = 0; jt < 8; ++jt) {
        f32x4 acc = {0.f, 0.f, 0.f, 0.f};
        const _Float16* wp = W1 + (size_t)(jt * 16 + l15) * DIM + kg * 8;
        #pragma unroll
        for (int kk = 0; kk < 4; ++kk)
            acc = MFMA16(a[kk], *(const f16x8*)(wp + kk * 32), acc);
        float bias = B1[jt * 16 + l15];
        #pragma unroll
        for (int r = 0; r < 4; ++r) {
            float v = acc[r] + bias;
            hbuf[wave][kg * 4 + r][jt * 16 + l15] = (_Float16)(v > 0.f ? v : 0.f);
        }
    }
    f16x8 h[4];
    #pragma unroll
    for (int kk = 0; kk < 4; ++kk)
        h[kk] = *(const f16x8*)(&hbuf[wave][l15][kk * 32 + kg * 8]);
    for (int jt = 0; jt < 8; ++jt) {
        f32x4 acc = {0.f, 0.f, 0.f, 0.f};
        const _Float16* wp = W2 + (size_t)(jt * 16 + l15) * DIM + kg * 8;
        #pragma unroll
        for (int kk = 0; kk < 4; ++kk)
            acc = MFMA16(h[kk], *(const f16x8*)(wp + kk * 32), acc);
        float bias = B2[jt * 16 + l15];
        #pragma unroll
        for (int r = 0; r < 4; ++r)
            Y[(size_t)(m0 + kg * 4 + r) * DIM + jt * 16 + l15] = (_Float16)(acc[r] + bias);
    }
}

// ---------------- GRUs ----------------
// clause GRU: x (f16) = l2c_aggr, h (f32) ; Wih,Whh f16 [384,128]
__global__ __launch_bounds__(256) void gru_c_kernel(
    const _Float16* __restrict__ X, const float* __restrict__ H,
    const _Float16* __restrict__ Wih, const _Float16* __restrict__ Whh,
    const float* __restrict__ bih, const float* __restrict__ bhh,
    float* __restrict__ Hout, int M)
{
    const int lane = threadIdx.x & 63;
    const int wave = threadIdx.x >> 6;
    const int m0 = blockIdx.x * 64 + wave * 16;
    if (m0 >= M) return;
    const int l15 = lane & 15;
    const int kg  = lane >> 4;

    f16x8 xa[4], ha[4];
    {
        const _Float16* xp = X + (size_t)(m0 + l15) * DIM + kg * 8;
        const float* hp = H + (size_t)(m0 + l15) * DIM + kg * 8;
        #pragma unroll
        for (int kk = 0; kk < 4; ++kk) {
            xa[kk] = *(const f16x8*)(xp + kk * 32);
            ha[kk] = frag_from_f32(hp + kk * 32);
        }
    }
    for (int jt = 0; jt < 8; ++jt) {
        const int j0 = jt * 16;
        f32x4 ar = {0,0,0,0}, az = {0,0,0,0}, agn = {0,0,0,0}, ahn = {0,0,0,0};
        const _Float16* wi = Wih + (size_t)(j0 + l15) * DIM + kg * 8;
        const _Float16* wh = Whh + (size_t)(j0 + l15) * DIM + kg * 8;
        #pragma unroll
        for (int kk = 0; kk < 4; ++kk) {
            const int o = kk * 32;
            ar  = MFMA16(xa[kk], *(const f16x8*)(wi + o), ar);
            az  = MFMA16(xa[kk], *(const f16x8*)(wi + 128 * DIM + o), az);
            agn = MFMA16(xa[kk], *(const f16x8*)(wi + 256 * DIM + o), agn);
            ar  = MFMA16(ha[kk], *(const f16x8*)(wh + o), ar);
            az  = MFMA16(ha[kk], *(const f16x8*)(wh + 128 * DIM + o), az);
            ahn = MFMA16(ha[kk], *(const f16x8*)(wh + 256 * DIM + o), ahn);
        }
        const int col = j0 + l15;
        float brc = bih[col] + bhh[col];
        float bzc = bih[128 + col] + bhh[128 + col];
        float bgn = bih[256 + col];
        float bhn = bhh[256 + col];
        #pragma unroll
        for (int r = 0; r < 4; ++r) {
            int m = m0 + kg * 4 + r;
            float rg = sigmoidf_(ar[r] + brc);
            float zg = sigmoidf_(az[r] + bzc);
            float ng = tanhf_(agn[r] + bgn + rg * (ahn[r] + bhn));
            float h = H[(size_t)m * DIM + col];
            Hout[(size_t)m * DIM + col] = (1.f - zg) * ng + zg * h;
        }
    }
}

// literal GRU: x = concat(c2l_aggr (f16), L[m^1] (f32)), h = L[m]
__global__ __launch_bounds__(256) void gru_l_kernel(
    const _Float16* __restrict__ X, const float* __restrict__ L,
    const _Float16* __restrict__ Wih, const _Float16* __restrict__ Whh,
    const float* __restrict__ bih, const float* __restrict__ bhh,
    float* __restrict__ Lout, int M)
{
    const int lane = threadIdx.x & 63;
    const int wave = threadIdx.x >> 6;
    const int m0 = blockIdx.x * 64 + wave * 16;
    if (m0 >= M) return;
    const int l15 = lane & 15;
    const int kg  = lane >> 4;
    const int mrow = m0 + l15;

    f16x8 xa[4], xs[4], ha[4];
    {
        const _Float16* xp = X + (size_t)mrow * DIM + kg * 8;
        const float* sp = L + (size_t)(mrow ^ 1) * DIM + kg * 8;
        const float* hp = L + (size_t)mrow * DIM + kg * 8;
        #pragma unroll
        for (int kk = 0; kk < 4; ++kk) {
            xa[kk] = *(const f16x8*)(xp + kk * 32);
            xs[kk] = frag_from_f32(sp + kk * 32);
            ha[kk] = frag_from_f32(hp + kk * 32);
        }
    }
    for (int jt = 0; jt < 8; ++jt) {
        const int j0 = jt * 16;
        f32x4 ar = {0,0,0,0}, az = {0,0,0,0}, agn = {0,0,0,0}, ahn = {0,0,0,0};
        const _Float16* wi = Wih + (size_t)(j0 + l15) * 256 + kg * 8;
        const _Float16* wh = Whh + (size_t)(j0 + l15) * DIM + kg * 8;
        #pragma unroll
        for (int kk = 0; kk < 4; ++kk) {
            const int o = kk * 32;
            ar  = MFMA16(xa[kk], *(const f16x8*)(wi + o), ar);
            az  = MFMA16(xa[kk], *(const f16x8*)(wi + 128 * 256 + o), az);
            agn = MFMA16(xa[kk], *(const f16x8*)(wi + 256 * 256 + o), agn);
            ar  = MFMA16(xs[kk], *(const f16x8*)(wi + 128 + o), ar);
            az  = MFMA16(xs[kk], *(const f16x8*)(wi + 128 * 256 + 128 + o), az);
            agn = MFMA16(xs[kk], *(const f16x8*)(wi + 256 * 256 + 128 + o), agn);
            ar  = MFMA16(ha[kk], *(const f16x8*)(wh + o), ar);
            az  = MFMA16(ha[kk], *(const f16x8*)(wh + 128 * DIM + o), az);
            ahn = MFMA16(ha[kk], *(const f16x8*)(wh + 256 * DIM + o), ahn);
        }
        const int col = j0 + l15;
        float brc = bih[col] + bhh[col];
        float bzc = bih[128 + col] + bhh[128 + col];
        float bgn = bih[256 + col];
        float bhn = bhh[256 + col];
        #pragma unroll
        for (int r = 0; r < 4; ++r) {
            int m = m0 + kg * 4 + r;
            float rg = sigmoidf_(ar[r] + brc);
            float zg = sigmoidf_(az[r] + bzc);
            float ng = tanhf_(agn[r] + bgn + rg * (ahn[r] + bhn));
            float h = L[(size_t)m * DIM + col];
            Lout[(size_t)m * DIM + col] = (1.f - zg) * ng + zg * h;
        }
    }
}

extern "C" void kernel_launch(void* const* d_in, const int* in_sizes, int n_in,
                              void* d_out, int out_size, void* d_ws, size_t ws_size,
                              hipStream_t stream)
{
    const int*   l_edge = (const int*)d_in[2];
    const int*   c_edge = (const int*)d_in[3];
    const float* l_emb0 = (const float*)d_in[4];
    const float* c_emb0 = (const float*)d_in[5];
    const float* l2c_w1 = (const float*)d_in[6];
    const float* l2c_b1 = (const float*)d_in[7];
    const float* l2c_w2 = (const float*)d_in[8];
    const float* l2c_b2 = (const float*)d_in[9];
    const float* c2l_w1 = (const float*)d_in[10];
    const float* c2l_b1 = (const float*)d_in[11];
    const float* c2l_w2 = (const float*)d_in[12];
    const float* c2l_b2 = (const float*)d_in[13];
    const float* c_w_ih = (const float*)d_in[14];
    const float* c_w_hh = (const float*)d_in[15];
    const float* c_b_ih = (const float*)d_in[16];
    const float* c_b_hh = (const float*)d_in[17];
    const float* l_w_ih = (const float*)d_in[18];
    const float* l_w_hh = (const float*)d_in[19];
    const float* l_b_ih = (const float*)d_in[20];
    const float* l_b_hh = (const float*)d_in[21];

    const int n_edges = in_sizes[2];
    const int Lsz = in_sizes[4] / DIM;   // 80000
    const int Csz = in_sizes[5] / DIM;   // 160000

    float* OUT_L = (float*)d_out;                                  // (5, Lsz, 128)
    float* OUT_C = OUT_L + (size_t)(NITERS + 1) * Lsz * DIM;       // (5, Csz, 128)

    char* wsp = (char*)d_ws;
    auto carve = [&](size_t bytes) -> void* {
        void* p = (void*)wsp;
        wsp += (bytes + 255) & ~(size_t)255;
        return p;
    };
    _Float16* c_msg    = (_Float16*)carve((size_t)Csz * DIM * 2);
    _Float16* l_msg    = (_Float16*)carve((size_t)Lsz * DIM * 2);
    _Float16* l2c_aggr = (_Float16*)carve((size_t)Csz * DIM * 2);
    _Float16* c2l_aggr = (_Float16*)carve((size_t)Lsz * DIM * 2);
    int* deg_c = (int*)carve((size_t)(Csz)     * 4);
    int* deg_l = (int*)carve((size_t)(Lsz)     * 4);
    int* cur_c = (int*)carve((size_t)(Csz)     * 4);
    int* cur_l = (int*)carve((size_t)(Lsz)     * 4);
    int* rs_c  = (int*)carve((size_t)(Csz + 1) * 4);
    int* rs_l  = (int*)carve((size_t)(Lsz + 1) * 4);
    int* csr_c = (int*)carve((size_t)n_edges   * 4);
    int* csr_l = (int*)carve((size_t)n_edges   * 4);
    int* bsum_c = (int*)carve(256 * 4);
    int* bsum_l = (int*)carve(256 * 4);
    _Float16* hw_l2c1 = (_Float16*)carve((size_t)DIM * DIM * 2);
    _Float16* hw_l2c2 = (_Float16*)carve((size_t)DIM * DIM * 2);
    _Float16* hw_c2l1 = (_Float16*)carve((size_t)DIM * DIM * 2);
    _Float16* hw_c2l2 = (_Float16*)carve((size_t)DIM * DIM * 2);
    _Float16* hw_cih  = (_Float16*)carve((size_t)3 * DIM * DIM * 2);
    _Float16* hw_chh  = (_Float16*)carve((size_t)3 * DIM * DIM * 2);
    _Float16* hw_lih  = (_Float16*)carve((size_t)3 * DIM * 2 * DIM * 2);
    _Float16* hw_lhh  = (_Float16*)carve((size_t)3 * DIM * DIM * 2);

    auto conv = [&](const float* s, _Float16* d, int n) {
        f32_to_f16_kernel<<<(n + 255) / 256, 256, 0, stream>>>(s, d, n);
    };
    conv(l2c_w1, hw_l2c1, DIM * DIM);
    conv(l2c_w2, hw_l2c2, DIM * DIM);
    conv(c2l_w1, hw_c2l1, DIM * DIM);
    conv(c2l_w2, hw_c2l2, DIM * DIM);
    conv(c_w_ih, hw_cih, 3 * DIM * DIM);
    conv(c_w_hh, hw_chh, 3 * DIM * DIM);
    conv(l_w_ih, hw_lih, 3 * DIM * 2 * DIM);
    conv(l_w_hh, hw_lhh, 3 * DIM * DIM);

    // initial state slices
    hipMemcpyAsync(OUT_L, l_emb0, (size_t)Lsz * DIM * 4, hipMemcpyDeviceToDevice, stream);
    hipMemcpyAsync(OUT_C, c_emb0, (size_t)Csz * DIM * 4, hipMemcpyDeviceToDevice, stream);

    // ---- CSR build (both directions), once per launch ----
    hipMemsetAsync(deg_c, 0, (size_t)Csz * 4, stream);
    hipMemsetAsync(deg_l, 0, (size_t)Lsz * 4, stream);
    hipMemsetAsync(cur_c, 0, (size_t)Csz * 4, stream);
    hipMemsetAsync(cur_l, 0, (size_t)Lsz * 4, stream);

    const int eb = (n_edges + 255) / 256;
    hist_kernel<<<eb, 256, 0, stream>>>(c_edge, deg_c, n_edges);
    hist_kernel<<<eb, 256, 0, stream>>>(l_edge, deg_l, n_edges);

    const int nb_c = (Csz + 1023) / 1024;
    const int nb_l = (Lsz + 1023) / 1024;
    scan_reduce<<<nb_c, 256, 0, stream>>>(deg_c, bsum_c, Csz);
    scan_reduce<<<nb_l, 256, 0, stream>>>(deg_l, bsum_l, Lsz);
    scan_blocksums<<<1, 256, 0, stream>>>(bsum_c, nb_c);
    scan_blocksums<<<1, 256, 0, stream>>>(bsum_l, nb_l);
    scan_write<<<nb_c, 256, 0, stream>>>(deg_c, bsum_c, rs_c, Csz);
    scan_write<<<nb_l, 256, 0, stream>>>(deg_l, bsum_l, rs_l, Lsz);
    set_int_kernel<<<1, 1, 0, stream>>>(rs_c + Csz, n_edges);
    set_int_kernel<<<1, 1, 0, stream>>>(rs_l + Lsz, n_edges);
    fill_kernel<<<eb, 256, 0, stream>>>(l_edge, c_edge, rs_c, cur_c, csr_c, n_edges);
    fill_kernel<<<eb, 256, 0, stream>>>(c_edge, l_edge, rs_l, cur_l, csr_l, n_edges);

    // ---- main loop ----
    for (int t = 0; t < NITERS; ++t) {
        const float* Lt = OUT_L + (size_t)t * Lsz * DIM;
        const float* Ct = OUT_C + (size_t)t * Csz * DIM;
        float* Lt1 = OUT_L + (size_t)(t + 1) * Lsz * DIM;
        float* Ct1 = OUT_C + (size_t)(t + 1) * Csz * DIM;

        mlp_kernel<<<(Lsz + 63) / 64, 256, 0, stream>>>(Lt, hw_l2c1, l2c_b1, hw_l2c2, l2c_b2, l_msg, Lsz);
        mlp_kernel<<<(Csz + 63) / 64, 256, 0, stream>>>(Ct, hw_c2l1, c2l_b1, hw_c2l2, c2l_b2, c_msg, Csz);
        gather_kernel<<<(Csz + 3) / 4, 256, 0, stream>>>(l_msg, rs_c, csr_c, l2c_aggr, Csz);
        gather_kernel<<<(Lsz + 3) / 4, 256, 0, stream>>>(c_msg, rs_l, csr_l, c2l_aggr, Lsz);
        gru_c_kernel<<<(Csz + 63) / 64, 256, 0, stream>>>(l2c_aggr, Ct, hw_cih, hw_chh, c_b_ih, c_b_hh, Ct1, Csz);
        gru_l_kernel<<<(Lsz + 63) / 64, 256, 0, stream>>>(c2l_aggr, Lt, hw_lih, hw_lhh, l_b_ih, l_b_hh, Lt1, Lsz);
    }
}

// Round 3
// 1985.645 us; speedup vs baseline: 4.4949x; 1.4449x over previous
//
#include <hip/hip_runtime.h>

#define DIM 128
#define NITERS 4

typedef _Float16 f16x8 __attribute__((ext_vector_type(8)));
typedef _Float16 f16x4 __attribute__((ext_vector_type(4)));
typedef _Float16 f16x2 __attribute__((ext_vector_type(2)));
typedef float f32x4 __attribute__((ext_vector_type(4)));

#define MFMA16(a, b, c) __builtin_amdgcn_mfma_f32_16x16x32_f16((a), (b), (c), 0, 0, 0)

__device__ __forceinline__ float sigmoidf_(float x) { return 1.f / (1.f + __expf(-x)); }
__device__ __forceinline__ float tanhf_(float x) { return 1.f - 2.f / (__expf(2.f * x) + 1.f); }

__global__ void f32_to_f16_kernel(const float* __restrict__ in, _Float16* __restrict__ out, int n) {
    int i = blockIdx.x * 256 + threadIdx.x;
    if (i < n) out[i] = (_Float16)in[i];
}

// copy f32 src -> f32 out slice AND f16 mirror, vectorized (n % 4 == 0)
__global__ __launch_bounds__(256) void init_state_kernel(const float* __restrict__ src,
                                                         float* __restrict__ out32,
                                                         _Float16* __restrict__ out16, int n4) {
    int i = blockIdx.x * 256 + threadIdx.x;
    if (i >= n4) return;
    float4 v = ((const float4*)src)[i];
    ((float4*)out32)[i] = v;
    f16x4 h; h[0] = (_Float16)v.x; h[1] = (_Float16)v.y; h[2] = (_Float16)v.z; h[3] = (_Float16)v.w;
    ((f16x4*)out16)[i] = h;
}

// ---------------- CSR build (once per launch) ----------------

__global__ __launch_bounds__(256) void hist_kernel(const int* __restrict__ idx, int* __restrict__ deg, int n) {
    int i = blockIdx.x * 256 + threadIdx.x;
    if (i < n) atomicAdd(deg + idx[i], 1);
}

__global__ __launch_bounds__(256) void scan_reduce(const int* __restrict__ deg, int* __restrict__ bsum, int n) {
    __shared__ int sh[256];
    const int t = threadIdx.x;
    const int base = blockIdx.x * 1024 + t * 4;
    int v = 0;
    #pragma unroll
    for (int k = 0; k < 4; ++k) { int i = base + k; if (i < n) v += deg[i]; }
    sh[t] = v; __syncthreads();
    for (int off = 128; off > 0; off >>= 1) {
        if (t < off) sh[t] += sh[t + off];
        __syncthreads();
    }
    if (t == 0) bsum[blockIdx.x] = sh[0];
}

__global__ __launch_bounds__(256) void scan_blocksums(int* __restrict__ bsum, int nb) {
    __shared__ int sh[256];
    const int t = threadIdx.x;
    int v = (t < nb) ? bsum[t] : 0;
    sh[t] = v; __syncthreads();
    for (int off = 1; off < 256; off <<= 1) {
        int u = (t >= off) ? sh[t - off] : 0;
        __syncthreads();
        sh[t] += u;
        __syncthreads();
    }
    if (t < nb) bsum[t] = sh[t] - v;
}

__global__ __launch_bounds__(256) void scan_write(const int* __restrict__ deg, const int* __restrict__ bsum,
                                                  int* __restrict__ rs, int n) {
    __shared__ int sh[256];
    const int t = threadIdx.x;
    const int base = blockIdx.x * 1024 + t * 4;
    int v[4], p[4], s = 0;
    #pragma unroll
    for (int k = 0; k < 4; ++k) {
        int i = base + k;
        v[k] = (i < n) ? deg[i] : 0;
        p[k] = s; s += v[k];
    }
    sh[t] = s; __syncthreads();
    for (int off = 1; off < 256; off <<= 1) {
        int u = (t >= off) ? sh[t - off] : 0;
        __syncthreads();
        sh[t] += u;
        __syncthreads();
    }
    int off0 = bsum[blockIdx.x] + (sh[t] - s);
    #pragma unroll
    for (int k = 0; k < 4; ++k) {
        int i = base + k;
        if (i < n) rs[i] = off0 + p[k];
    }
}

__global__ void set_int_kernel(int* p, int v) { *p = v; }

__global__ __launch_bounds__(256) void fill_kernel(const int* __restrict__ src, const int* __restrict__ dst,
                                                   const int* __restrict__ rs, int* __restrict__ cur,
                                                   int* __restrict__ csr, int n) {
    int e = blockIdx.x * 256 + threadIdx.x;
    if (e >= n) return;
    int d = dst[e];
    int slot = atomicAdd(cur + d, 1);
    csr[rs[d] + slot] = src[e];
}

// ---------------- pull-based aggregation ----------------
// one wave per dest row; lane owns 2 dims; 4 sources in flight (csr idx wave-uniform)
__global__ __launch_bounds__(256) void gather_kernel(const _Float16* __restrict__ msg,
                                                     const int* __restrict__ rs, const int* __restrict__ csr,
                                                     _Float16* __restrict__ aggr, int n_dst) {
    const int lane = threadIdx.x & 63;
    const int wave = threadIdx.x >> 6;
    const int d = blockIdx.x * 4 + wave;
    if (d >= n_dst) return;
    const int beg = rs[d], end = rs[d + 1];
    float ax = 0.f, ay = 0.f, bx = 0.f, by = 0.f, cx = 0.f, cy = 0.f, dx = 0.f, dy = 0.f;
    int j = beg;
    const int col = lane * 2;
    for (; j + 4 <= end; j += 4) {
        int s0 = csr[j], s1 = csr[j + 1], s2 = csr[j + 2], s3 = csr[j + 3];
        f16x2 v0 = *(const f16x2*)(msg + (size_t)s0 * DIM + col);
        f16x2 v1 = *(const f16x2*)(msg + (size_t)s1 * DIM + col);
        f16x2 v2 = *(const f16x2*)(msg + (size_t)s2 * DIM + col);
        f16x2 v3 = *(const f16x2*)(msg + (size_t)s3 * DIM + col);
        ax += (float)v0[0]; ay += (float)v0[1];
        bx += (float)v1[0]; by += (float)v1[1];
        cx += (float)v2[0]; cy += (float)v2[1];
        dx += (float)v3[0]; dy += (float)v3[1];
    }
    for (; j < end; ++j) {
        int s = csr[j];
        f16x2 v = *(const f16x2*)(msg + (size_t)s * DIM + col);
        ax += (float)v[0]; ay += (float)v[1];
    }
    float ox = (ax + bx) + (cx + dx), oy = (ay + by) + (cy + dy);
    f16x2 o; o[0] = (_Float16)ox; o[1] = (_Float16)oy;
    *(f16x2*)(aggr + (size_t)d * DIM + col) = o;
}

// ---------------- MLP ----------------
// y = relu(x @ W1^T + b1) @ W2^T + b2 ; x f16 mirror [M,128], y f16 [M,128]
// 32 rows/wave (2 subtiles) -> each weight fragment feeds 2 MFMAs
__global__ __launch_bounds__(256) void mlp_kernel(
    const _Float16* __restrict__ X, const _Float16* __restrict__ W1, const float* __restrict__ B1,
    const _Float16* __restrict__ W2, const float* __restrict__ B2,
    _Float16* __restrict__ Y, int M)
{
    __shared__ _Float16 hbuf[4][32][DIM + 8];
    const int lane = threadIdx.x & 63;
    const int wave = threadIdx.x >> 6;
    const int m0 = blockIdx.x * 128 + wave * 32;
    if (m0 >= M) return;
    const int l15 = lane & 15;
    const int kg  = lane >> 4;

    f16x8 a[2][4];
    #pragma unroll
    for (int s = 0; s < 2; ++s) {
        const _Float16* xp = X + (size_t)(m0 + s * 16 + l15) * DIM + kg * 8;
        #pragma unroll
        for (int kk = 0; kk < 4; ++kk) a[s][kk] = *(const f16x8*)(xp + kk * 32);
    }
    #pragma unroll
    for (int jt = 0; jt < 8; ++jt) {
        f32x4 acc0 = {0,0,0,0}, acc1 = {0,0,0,0};
        const _Float16* wp = W1 + (size_t)(jt * 16 + l15) * DIM + kg * 8;
        #pragma unroll
        for (int kk = 0; kk < 4; ++kk) {
            f16x8 w = *(const f16x8*)(wp + kk * 32);
            acc0 = MFMA16(a[0][kk], w, acc0);
            acc1 = MFMA16(a[1][kk], w, acc1);
        }
        float bias = B1[jt * 16 + l15];
        #pragma unroll
        for (int r = 0; r < 4; ++r) {
            float v0 = acc0[r] + bias, v1 = acc1[r] + bias;
            hbuf[wave][kg * 4 + r][jt * 16 + l15]      = (_Float16)(v0 > 0.f ? v0 : 0.f);
            hbuf[wave][16 + kg * 4 + r][jt * 16 + l15] = (_Float16)(v1 > 0.f ? v1 : 0.f);
        }
    }
    f16x8 h[2][4];
    #pragma unroll
    for (int s = 0; s < 2; ++s)
        #pragma unroll
        for (int kk = 0; kk < 4; ++kk)
            h[s][kk] = *(const f16x8*)(&hbuf[wave][s * 16 + l15][kk * 32 + kg * 8]);
    #pragma unroll
    for (int jt = 0; jt < 8; ++jt) {
        f32x4 acc0 = {0,0,0,0}, acc1 = {0,0,0,0};
        const _Float16* wp = W2 + (size_t)(jt * 16 + l15) * DIM + kg * 8;
        #pragma unroll
        for (int kk = 0; kk < 4; ++kk) {
            f16x8 w = *(const f16x8*)(wp + kk * 32);
            acc0 = MFMA16(h[0][kk], w, acc0);
            acc1 = MFMA16(h[1][kk], w, acc1);
        }
        float bias = B2[jt * 16 + l15];
        #pragma unroll
        for (int r = 0; r < 4; ++r) {
            Y[(size_t)(m0 + kg * 4 + r) * DIM + jt * 16 + l15]      = (_Float16)(acc0[r] + bias);
            Y[(size_t)(m0 + 16 + kg * 4 + r) * DIM + jt * 16 + l15] = (_Float16)(acc1[r] + bias);
        }
    }
}

// ---------------- GRUs ----------------
// clause GRU: x f16 aggr, state via f16 mirror; writes f32 out + f16 mirror
__global__ __launch_bounds__(256) void gru_c_kernel(
    const _Float16* __restrict__ X, const _Float16* __restrict__ Hh,
    const _Float16* __restrict__ Wih, const _Float16* __restrict__ Whh,
    const float* __restrict__ bih, const float* __restrict__ bhh,
    float* __restrict__ Hout, _Float16* __restrict__ Hmir, int M)
{
    const int lane = threadIdx.x & 63;
    const int wave = threadIdx.x >> 6;
    const int m0 = blockIdx.x * 128 + wave * 32;
    if (m0 >= M) return;
    const int l15 = lane & 15;
    const int kg  = lane >> 4;

    f16x8 xa[2][4], ha[2][4];
    #pragma unroll
    for (int s = 0; s < 2; ++s) {
        const _Float16* xp = X  + (size_t)(m0 + s * 16 + l15) * DIM + kg * 8;
        const _Float16* hp = Hh + (size_t)(m0 + s * 16 + l15) * DIM + kg * 8;
        #pragma unroll
        for (int kk = 0; kk < 4; ++kk) {
            xa[s][kk] = *(const f16x8*)(xp + kk * 32);
            ha[s][kk] = *(const f16x8*)(hp + kk * 32);
        }
    }
    #pragma unroll
    for (int jt = 0; jt < 8; ++jt) {
        const int j0 = jt * 16;
        f32x4 ar[2] = {{0,0,0,0},{0,0,0,0}}, az[2] = {{0,0,0,0},{0,0,0,0}};
        f32x4 an[2] = {{0,0,0,0},{0,0,0,0}}, ah[2] = {{0,0,0,0},{0,0,0,0}};
        const _Float16* wi = Wih + (size_t)(j0 + l15) * DIM + kg * 8;
        const _Float16* wh = Whh + (size_t)(j0 + l15) * DIM + kg * 8;
        #pragma unroll
        for (int kk = 0; kk < 4; ++kk) {
            const int o = kk * 32;
            f16x8 wir = *(const f16x8*)(wi + o);
            f16x8 wiz = *(const f16x8*)(wi + 128 * DIM + o);
            f16x8 win = *(const f16x8*)(wi + 256 * DIM + o);
            f16x8 whr = *(const f16x8*)(wh + o);
            f16x8 whz = *(const f16x8*)(wh + 128 * DIM + o);
            f16x8 whn = *(const f16x8*)(wh + 256 * DIM + o);
            #pragma unroll
            for (int s = 0; s < 2; ++s) {
                ar[s] = MFMA16(xa[s][kk], wir, ar[s]);
                ar[s] = MFMA16(ha[s][kk], whr, ar[s]);
                az[s] = MFMA16(xa[s][kk], wiz, az[s]);
                az[s] = MFMA16(ha[s][kk], whz, az[s]);
                an[s] = MFMA16(xa[s][kk], win, an[s]);
                ah[s] = MFMA16(ha[s][kk], whn, ah[s]);
            }
        }
        const int col = j0 + l15;
        float brc = bih[col] + bhh[col];
        float bzc = bih[128 + col] + bhh[128 + col];
        float bgn = bih[256 + col];
        float bhn = bhh[256 + col];
        #pragma unroll
        for (int s = 0; s < 2; ++s)
            #pragma unroll
            for (int r = 0; r < 4; ++r) {
                int m = m0 + s * 16 + kg * 4 + r;
                float rg = sigmoidf_(ar[s][r] + brc);
                float zg = sigmoidf_(az[s][r] + bzc);
                float ng = tanhf_(an[s][r] + bgn + rg * (ah[s][r] + bhn));
                float h = (float)Hh[(size_t)m * DIM + col];
                float o = (1.f - zg) * ng + zg * h;
                Hout[(size_t)m * DIM + col] = o;
                Hmir[(size_t)m * DIM + col] = (_Float16)o;
            }
    }
}

// literal GRU: x = concat(c2l_aggr f16, Lmirror[m^1]), h = Lmirror[m]
__global__ __launch_bounds__(256) void gru_l_kernel(
    const _Float16* __restrict__ X, const _Float16* __restrict__ Lh,
    const _Float16* __restrict__ Wih, const _Float16* __restrict__ Whh,
    const float* __restrict__ bih, const float* __restrict__ bhh,
    float* __restrict__ Lout, _Float16* __restrict__ Lmir, int M)
{
    const int lane = threadIdx.x & 63;
    const int wave = threadIdx.x >> 6;
    const int m0 = blockIdx.x * 128 + wave * 32;
    if (m0 >= M) return;
    const int l15 = lane & 15;
    const int kg  = lane >> 4;

    f16x8 xa[2][4], xs[2][4], ha[2][4];
    #pragma unroll
    for (int s = 0; s < 2; ++s) {
        const int row = m0 + s * 16 + l15;
        const _Float16* xp = X  + (size_t)row * DIM + kg * 8;
        const _Float16* sp = Lh + (size_t)(row ^ 1) * DIM + kg * 8;
        const _Float16* hp = Lh + (size_t)row * DIM + kg * 8;
        #pragma unroll
        for (int kk = 0; kk < 4; ++kk) {
            xa[s][kk] = *(const f16x8*)(xp + kk * 32);
            xs[s][kk] = *(const f16x8*)(sp + kk * 32);
            ha[s][kk] = *(const f16x8*)(hp + kk * 32);
        }
    }
    #pragma unroll
    for (int jt = 0; jt < 8; ++jt) {
        const int j0 = jt * 16;
        f32x4 ar[2] = {{0,0,0,0},{0,0,0,0}}, az[2] = {{0,0,0,0},{0,0,0,0}};
        f32x4 an[2] = {{0,0,0,0},{0,0,0,0}}, ah[2] = {{0,0,0,0},{0,0,0,0}};
        const _Float16* wi = Wih + (size_t)(j0 + l15) * 256 + kg * 8;
        const _Float16* wh = Whh + (size_t)(j0 + l15) * DIM + kg * 8;
        #pragma unroll
        for (int kk = 0; kk < 4; ++kk) {
            const int o = kk * 32;
            f16x8 wir = *(const f16x8*)(wi + o);
            f16x8 wiz = *(const f16x8*)(wi + 128 * 256 + o);
            f16x8 win = *(const f16x8*)(wi + 256 * 256 + o);
            f16x8 vir = *(const f16x8*)(wi + 128 + o);
            f16x8 viz = *(const f16x8*)(wi + 128 * 256 + 128 + o);
            f16x8 vin = *(const f16x8*)(wi + 256 * 256 + 128 + o);
            f16x8 whr = *(const f16x8*)(wh + o);
            f16x8 whz = *(const f16x8*)(wh + 128 * DIM + o);
            f16x8 whn = *(const f16x8*)(wh + 256 * DIM + o);
            #pragma unroll
            for (int s = 0; s < 2; ++s) {
                ar[s] = MFMA16(xa[s][kk], wir, ar[s]);
                ar[s] = MFMA16(xs[s][kk], vir, ar[s]);
                ar[s] = MFMA16(ha[s][kk], whr, ar[s]);
                az[s] = MFMA16(xa[s][kk], wiz, az[s]);
                az[s] = MFMA16(xs[s][kk], viz, az[s]);
                az[s] = MFMA16(ha[s][kk], whz, az[s]);
                an[s] = MFMA16(xa[s][kk], win, an[s]);
                an[s] = MFMA16(xs[s][kk], vin, an[s]);
                ah[s] = MFMA16(ha[s][kk], whn, ah[s]);
            }
        }
        const int col = j0 + l15;
        float brc = bih[col] + bhh[col];
        float bzc = bih[128 + col] + bhh[128 + col];
        float bgn = bih[256 + col];
        float bhn = bhh[256 + col];
        #pragma unroll
        for (int s = 0; s < 2; ++s)
            #pragma unroll
            for (int r = 0; r < 4; ++r) {
                int m = m0 + s * 16 + kg * 4 + r;
                float rg = sigmoidf_(ar[s][r] + brc);
                float zg = sigmoidf_(az[s][r] + bzc);
                float ng = tanhf_(an[s][r] + bgn + rg * (ah[s][r] + bhn));
                float h = (float)Lh[(size_t)m * DIM + col];
                float o = (1.f - zg) * ng + zg * h;
                Lout[(size_t)m * DIM + col] = o;
                Lmir[(size_t)m * DIM + col] = (_Float16)o;
            }
    }
}

extern "C" void kernel_launch(void* const* d_in, const int* in_sizes, int n_in,
                              void* d_out, int out_size, void* d_ws, size_t ws_size,
                              hipStream_t stream)
{
    const int*   l_edge = (const int*)d_in[2];
    const int*   c_edge = (const int*)d_in[3];
    const float* l_emb0 = (const float*)d_in[4];
    const float* c_emb0 = (const float*)d_in[5];
    const float* l2c_w1 = (const float*)d_in[6];
    const float* l2c_b1 = (const float*)d_in[7];
    const float* l2c_w2 = (const float*)d_in[8];
    const float* l2c_b2 = (const float*)d_in[9];
    const float* c2l_w1 = (const float*)d_in[10];
    const float* c2l_b1 = (const float*)d_in[11];
    const float* c2l_w2 = (const float*)d_in[12];
    const float* c2l_b2 = (const float*)d_in[13];
    const float* c_w_ih = (const float*)d_in[14];
    const float* c_w_hh = (const float*)d_in[15];
    const float* c_b_ih = (const float*)d_in[16];
    const float* c_b_hh = (const float*)d_in[17];
    const float* l_w_ih = (const float*)d_in[18];
    const float* l_w_hh = (const float*)d_in[19];
    const float* l_b_ih = (const float*)d_in[20];
    const float* l_b_hh = (const float*)d_in[21];

    const int n_edges = in_sizes[2];
    const int Lsz = in_sizes[4] / DIM;   // 80000
    const int Csz = in_sizes[5] / DIM;   // 160000

    float* OUT_L = (float*)d_out;                                  // (5, Lsz, 128)
    float* OUT_C = OUT_L + (size_t)(NITERS + 1) * Lsz * DIM;       // (5, Csz, 128)

    char* wsp = (char*)d_ws;
    auto carve = [&](size_t bytes) -> void* {
        void* p = (void*)wsp;
        wsp += (bytes + 255) & ~(size_t)255;
        return p;
    };
    _Float16* c_msg    = (_Float16*)carve((size_t)Csz * DIM * 2);
    _Float16* l_msg    = (_Float16*)carve((size_t)Lsz * DIM * 2);
    _Float16* l2c_aggr = (_Float16*)carve((size_t)Csz * DIM * 2);
    _Float16* c2l_aggr = (_Float16*)carve((size_t)Lsz * DIM * 2);
    _Float16* Ch0      = (_Float16*)carve((size_t)Csz * DIM * 2);
    _Float16* Ch1      = (_Float16*)carve((size_t)Csz * DIM * 2);
    _Float16* Lh0      = (_Float16*)carve((size_t)Lsz * DIM * 2);
    _Float16* Lh1      = (_Float16*)carve((size_t)Lsz * DIM * 2);
    int* deg_c = (int*)carve((size_t)(Csz)     * 4);
    int* deg_l = (int*)carve((size_t)(Lsz)     * 4);
    int* cur_c = (int*)carve((size_t)(Csz)     * 4);
    int* cur_l = (int*)carve((size_t)(Lsz)     * 4);
    int* rs_c  = (int*)carve((size_t)(Csz + 1) * 4);
    int* rs_l  = (int*)carve((size_t)(Lsz + 1) * 4);
    int* csr_c = (int*)carve((size_t)n_edges   * 4);
    int* csr_l = (int*)carve((size_t)n_edges   * 4);
    int* bsum_c = (int*)carve(256 * 4);
    int* bsum_l = (int*)carve(256 * 4);
    _Float16* hw_l2c1 = (_Float16*)carve((size_t)DIM * DIM * 2);
    _Float16* hw_l2c2 = (_Float16*)carve((size_t)DIM * DIM * 2);
    _Float16* hw_c2l1 = (_Float16*)carve((size_t)DIM * DIM * 2);
    _Float16* hw_c2l2 = (_Float16*)carve((size_t)DIM * DIM * 2);
    _Float16* hw_cih  = (_Float16*)carve((size_t)3 * DIM * DIM * 2);
    _Float16* hw_chh  = (_Float16*)carve((size_t)3 * DIM * DIM * 2);
    _Float16* hw_lih  = (_Float16*)carve((size_t)3 * DIM * 2 * DIM * 2);
    _Float16* hw_lhh  = (_Float16*)carve((size_t)3 * DIM * DIM * 2);

    auto conv = [&](const float* s, _Float16* d, int n) {
        f32_to_f16_kernel<<<(n + 255) / 256, 256, 0, stream>>>(s, d, n);
    };
    conv(l2c_w1, hw_l2c1, DIM * DIM);
    conv(l2c_w2, hw_l2c2, DIM * DIM);
    conv(c2l_w1, hw_c2l1, DIM * DIM);
    conv(c2l_w2, hw_c2l2, DIM * DIM);
    conv(c_w_ih, hw_cih, 3 * DIM * DIM);
    conv(c_w_hh, hw_chh, 3 * DIM * DIM);
    conv(l_w_ih, hw_lih, 3 * DIM * 2 * DIM);
    conv(l_w_hh, hw_lhh, 3 * DIM * DIM);

    // initial slices + f16 mirrors (fused)
    init_state_kernel<<<(Lsz * DIM / 4 + 255) / 256, 256, 0, stream>>>(l_emb0, OUT_L, Lh0, Lsz * DIM / 4);
    init_state_kernel<<<(Csz * DIM / 4 + 255) / 256, 256, 0, stream>>>(c_emb0, OUT_C, Ch0, Csz * DIM / 4);

    // ---- CSR build (both directions), once per launch ----
    hipMemsetAsync(deg_c, 0, (size_t)Csz * 4, stream);
    hipMemsetAsync(deg_l, 0, (size_t)Lsz * 4, stream);
    hipMemsetAsync(cur_c, 0, (size_t)Csz * 4, stream);
    hipMemsetAsync(cur_l, 0, (size_t)Lsz * 4, stream);

    const int eb = (n_edges + 255) / 256;
    hist_kernel<<<eb, 256, 0, stream>>>(c_edge, deg_c, n_edges);
    hist_kernel<<<eb, 256, 0, stream>>>(l_edge, deg_l, n_edges);

    const int nb_c = (Csz + 1023) / 1024;
    const int nb_l = (Lsz + 1023) / 1024;
    scan_reduce<<<nb_c, 256, 0, stream>>>(deg_c, bsum_c, Csz);
    scan_reduce<<<nb_l, 256, 0, stream>>>(deg_l, bsum_l, Lsz);
    scan_blocksums<<<1, 256, 0, stream>>>(bsum_c, nb_c);
    scan_blocksums<<<1, 256, 0, stream>>>(bsum_l, nb_l);
    scan_write<<<nb_c, 256, 0, stream>>>(deg_c, bsum_c, rs_c, Csz);
    scan_write<<<nb_l, 256, 0, stream>>>(deg_l, bsum_l, rs_l, Lsz);
    set_int_kernel<<<1, 1, 0, stream>>>(rs_c + Csz, n_edges);
    set_int_kernel<<<1, 1, 0, stream>>>(rs_l + Lsz, n_edges);
    fill_kernel<<<eb, 256, 0, stream>>>(l_edge, c_edge, rs_c, cur_c, csr_c, n_edges);
    fill_kernel<<<eb, 256, 0, stream>>>(c_edge, l_edge, rs_l, cur_l, csr_l, n_edges);

    // ---- main loop ----
    for (int t = 0; t < NITERS; ++t) {
        float* Lt1 = OUT_L + (size_t)(t + 1) * Lsz * DIM;
        float* Ct1 = OUT_C + (size_t)(t + 1) * Csz * DIM;
        const _Float16* Lm = (t & 1) ? Lh1 : Lh0;
        const _Float16* Cm = (t & 1) ? Ch1 : Ch0;
        _Float16* Lm1 = (t & 1) ? Lh0 : Lh1;
        _Float16* Cm1 = (t & 1) ? Ch0 : Ch1;

        mlp_kernel<<<(Lsz + 127) / 128, 256, 0, stream>>>(Lm, hw_l2c1, l2c_b1, hw_l2c2, l2c_b2, l_msg, Lsz);
        mlp_kernel<<<(Csz + 127) / 128, 256, 0, stream>>>(Cm, hw_c2l1, c2l_b1, hw_c2l2, c2l_b2, c_msg, Csz);
        gather_kernel<<<(Csz + 3) / 4, 256, 0, stream>>>(l_msg, rs_c, csr_c, l2c_aggr, Csz);
        gather_kernel<<<(Lsz + 3) / 4, 256, 0, stream>>>(c_msg, rs_l, csr_l, c2l_aggr, Lsz);
        gru_c_kernel<<<(Csz + 127) / 128, 256, 0, stream>>>(l2c_aggr, Cm, hw_cih, hw_chh, c_b_ih, c_b_hh, Ct1, Cm1, Csz);
        gru_l_kernel<<<(Lsz + 127) / 128, 256, 0, stream>>>(c2l_aggr, Lm, hw_lih, hw_lhh, l_b_ih, l_b_hh, Lt1, Lm1, Lsz);
    }
}

// Round 4
// 1875.148 us; speedup vs baseline: 4.7597x; 1.0589x over previous
//
#include <hip/hip_runtime.h>

#define DIM 128
#define NITERS 4

typedef _Float16 f16x8 __attribute__((ext_vector_type(8)));
typedef _Float16 f16x4 __attribute__((ext_vector_type(4)));
typedef _Float16 f16x2 __attribute__((ext_vector_type(2)));
typedef float f32x4 __attribute__((ext_vector_type(4)));

#define MFMA16(a, b, c) __builtin_amdgcn_mfma_f32_16x16x32_f16((a), (b), (c), 0, 0, 0)

__device__ __forceinline__ float sigmoidf_(float x) { return 1.f / (1.f + __expf(-x)); }
__device__ __forceinline__ float tanhf_(float x) { return 1.f - 2.f / (__expf(2.f * x) + 1.f); }

struct ConvDesc { const float* s; _Float16* d; int n; };

// all weight f32->f16 conversions in one launch; blockIdx.y selects descriptor
__global__ __launch_bounds__(256) void conv8_kernel(ConvDesc c0, ConvDesc c1, ConvDesc c2, ConvDesc c3,
                                                    ConvDesc c4, ConvDesc c5, ConvDesc c6, ConvDesc c7) {
    ConvDesc cd;
    switch (blockIdx.y) {
        case 0: cd = c0; break; case 1: cd = c1; break; case 2: cd = c2; break; case 3: cd = c3; break;
        case 4: cd = c4; break; case 5: cd = c5; break; case 6: cd = c6; break; default: cd = c7; break;
    }
    int i = blockIdx.x * 256 + threadIdx.x;
    if (i < cd.n) cd.d[i] = (_Float16)cd.s[i];
}

// copy f32 src -> f32 out slice AND f16 mirror, vectorized (n % 4 == 0)
__global__ __launch_bounds__(256) void init_state_kernel(const float* __restrict__ src,
                                                         float* __restrict__ out32,
                                                         _Float16* __restrict__ out16, int n4) {
    int i = blockIdx.x * 256 + threadIdx.x;
    if (i >= n4) return;
    float4 v = ((const float4*)src)[i];
    ((float4*)out32)[i] = v;
    f16x4 h; h[0] = (_Float16)v.x; h[1] = (_Float16)v.y; h[2] = (_Float16)v.z; h[3] = (_Float16)v.w;
    ((f16x4*)out16)[i] = h;
}

// ---------------- CSR build (once per launch) ----------------

__global__ __launch_bounds__(256) void hist_kernel(const int* __restrict__ idx, int* __restrict__ deg, int n) {
    int i = blockIdx.x * 256 + threadIdx.x;
    if (i < n) atomicAdd(deg + idx[i], 1);
}

__global__ __launch_bounds__(256) void scan_reduce(const int* __restrict__ deg, int* __restrict__ bsum, int n) {
    __shared__ int sh[256];
    const int t = threadIdx.x;
    const int base = blockIdx.x * 1024 + t * 4;
    int v = 0;
    #pragma unroll
    for (int k = 0; k < 4; ++k) { int i = base + k; if (i < n) v += deg[i]; }
    sh[t] = v; __syncthreads();
    for (int off = 128; off > 0; off >>= 1) {
        if (t < off) sh[t] += sh[t + off];
        __syncthreads();
    }
    if (t == 0) bsum[blockIdx.x] = sh[0];
}

__global__ __launch_bounds__(256) void scan_blocksums(int* __restrict__ bsum, int nb) {
    __shared__ int sh[256];
    const int t = threadIdx.x;
    int v = (t < nb) ? bsum[t] : 0;
    sh[t] = v; __syncthreads();
    for (int off = 1; off < 256; off <<= 1) {
        int u = (t >= off) ? sh[t - off] : 0;
        __syncthreads();
        sh[t] += u;
        __syncthreads();
    }
    if (t < nb) bsum[t] = sh[t] - v;
}

__global__ __launch_bounds__(256) void scan_write(const int* __restrict__ deg, const int* __restrict__ bsum,
                                                  int* __restrict__ rs, int n) {
    __shared__ int sh[256];
    const int t = threadIdx.x;
    const int base = blockIdx.x * 1024 + t * 4;
    int v[4], p[4], s = 0;
    #pragma unroll
    for (int k = 0; k < 4; ++k) {
        int i = base + k;
        v[k] = (i < n) ? deg[i] : 0;
        p[k] = s; s += v[k];
    }
    sh[t] = s; __syncthreads();
    for (int off = 1; off < 256; off <<= 1) {
        int u = (t >= off) ? sh[t - off] : 0;
        __syncthreads();
        sh[t] += u;
        __syncthreads();
    }
    int off0 = bsum[blockIdx.x] + (sh[t] - s);
    #pragma unroll
    for (int k = 0; k < 4; ++k) {
        int i = base + k;
        if (i < n) rs[i] = off0 + p[k];
    }
}

__global__ void set_int_kernel(int* p, int v) { *p = v; }

__global__ __launch_bounds__(256) void fill_kernel(const int* __restrict__ src, const int* __restrict__ dst,
                                                   const int* __restrict__ rs, int* __restrict__ cur,
                                                   int* __restrict__ csr, int n) {
    int e = blockIdx.x * 256 + threadIdx.x;
    if (e >= n) return;
    int d = dst[e];
    int slot = atomicAdd(cur + d, 1);
    csr[rs[d] + slot] = src[e];
}

// ---------------- pull-based aggregation ----------------
__global__ __launch_bounds__(256) void gather_kernel(const _Float16* __restrict__ msg,
                                                     const int* __restrict__ rs, const int* __restrict__ csr,
                                                     _Float16* __restrict__ aggr, int n_dst) {
    const int lane = threadIdx.x & 63;
    const int wave = threadIdx.x >> 6;
    const int d = blockIdx.x * 4 + wave;
    if (d >= n_dst) return;
    const int beg = rs[d], end = rs[d + 1];
    float ax = 0.f, ay = 0.f, bx = 0.f, by = 0.f, cx = 0.f, cy = 0.f, dx = 0.f, dy = 0.f;
    int j = beg;
    const int col = lane * 2;
    for (; j + 4 <= end; j += 4) {
        int s0 = csr[j], s1 = csr[j + 1], s2 = csr[j + 2], s3 = csr[j + 3];
        f16x2 v0 = *(const f16x2*)(msg + (size_t)s0 * DIM + col);
        f16x2 v1 = *(const f16x2*)(msg + (size_t)s1 * DIM + col);
        f16x2 v2 = *(const f16x2*)(msg + (size_t)s2 * DIM + col);
        f16x2 v3 = *(const f16x2*)(msg + (size_t)s3 * DIM + col);
        ax += (float)v0[0]; ay += (float)v0[1];
        bx += (float)v1[0]; by += (float)v1[1];
        cx += (float)v2[0]; cy += (float)v2[1];
        dx += (float)v3[0]; dy += (float)v3[1];
    }
    for (; j < end; ++j) {
        int s = csr[j];
        f16x2 v = *(const f16x2*)(msg + (size_t)s * DIM + col);
        ax += (float)v[0]; ay += (float)v[1];
    }
    float ox = (ax + bx) + (cx + dx), oy = (ay + by) + (cy + dy);
    f16x2 o; o[0] = (_Float16)ox; o[1] = (_Float16)oy;
    *(f16x2*)(aggr + (size_t)d * DIM + col) = o;
}

// ---------------- standalone MLP (prologue only) ----------------
__global__ __launch_bounds__(256) void mlp_kernel(
    const _Float16* __restrict__ X, const _Float16* __restrict__ W1, const float* __restrict__ B1,
    const _Float16* __restrict__ W2, const float* __restrict__ B2,
    _Float16* __restrict__ Y, int M)
{
    __shared__ _Float16 hbuf[4][32][136];
    const int lane = threadIdx.x & 63;
    const int wave = threadIdx.x >> 6;
    const int m0 = blockIdx.x * 128 + wave * 32;
    if (m0 >= M) return;
    const int l15 = lane & 15;
    const int kg  = lane >> 4;

    f16x8 a[2][4];
    #pragma unroll
    for (int s = 0; s < 2; ++s) {
        const _Float16* xp = X + (size_t)(m0 + s * 16 + l15) * DIM + kg * 8;
        #pragma unroll
        for (int kk = 0; kk < 4; ++kk) a[s][kk] = *(const f16x8*)(xp + kk * 32);
    }
    for (int jt = 0; jt < 8; ++jt) {
        f32x4 acc0 = {0,0,0,0}, acc1 = {0,0,0,0};
        const _Float16* wp = W1 + (size_t)(jt * 16 + l15) * DIM + kg * 8;
        #pragma unroll
        for (int kk = 0; kk < 4; ++kk) {
            f16x8 w = *(const f16x8*)(wp + kk * 32);
            acc0 = MFMA16(a[0][kk], w, acc0);
            acc1 = MFMA16(a[1][kk], w, acc1);
        }
        float bias = B1[jt * 16 + l15];
        #pragma unroll
        for (int r = 0; r < 4; ++r) {
            float v0 = acc0[r] + bias, v1 = acc1[r] + bias;
            hbuf[wave][kg * 4 + r][jt * 16 + l15]      = (_Float16)(v0 > 0.f ? v0 : 0.f);
            hbuf[wave][16 + kg * 4 + r][jt * 16 + l15] = (_Float16)(v1 > 0.f ? v1 : 0.f);
        }
    }
    f16x8 h[2][4];
    #pragma unroll
    for (int s = 0; s < 2; ++s)
        #pragma unroll
        for (int kk = 0; kk < 4; ++kk)
            h[s][kk] = *(const f16x8*)(&hbuf[wave][s * 16 + l15][kk * 32 + kg * 8]);
    for (int jt = 0; jt < 8; ++jt) {
        f32x4 acc0 = {0,0,0,0}, acc1 = {0,0,0,0};
        const _Float16* wp = W2 + (size_t)(jt * 16 + l15) * DIM + kg * 8;
        #pragma unroll
        for (int kk = 0; kk < 4; ++kk) {
            f16x8 w = *(const f16x8*)(wp + kk * 32);
            acc0 = MFMA16(h[0][kk], w, acc0);
            acc1 = MFMA16(h[1][kk], w, acc1);
        }
        float bias = B2[jt * 16 + l15];
        #pragma unroll
        for (int r = 0; r < 4; ++r) {
            Y[(size_t)(m0 + kg * 4 + r) * DIM + jt * 16 + l15]      = (_Float16)(acc0[r] + bias);
            Y[(size_t)(m0 + 16 + kg * 4 + r) * DIM + jt * 16 + l15] = (_Float16)(acc1[r] + bias);
        }
    }
}

// ---------------- fused GRU (+ next-iteration message MLP) ----------------
// clause: x = l2c_aggr (f16), h via f16 mirror. Writes f32 out + f16 mirror + (optional) next c_msg.
__global__ __launch_bounds__(256) void gru_c_fused(
    const _Float16* __restrict__ X, const _Float16* __restrict__ Hh,
    const _Float16* __restrict__ Wih, const _Float16* __restrict__ Whh,
    const float* __restrict__ bih, const float* __restrict__ bhh,
    float* __restrict__ Hout, _Float16* __restrict__ Hmir,
    const _Float16* __restrict__ W1, const float* __restrict__ B1,
    const _Float16* __restrict__ W2, const float* __restrict__ B2,
    _Float16* __restrict__ Msg, int M, int do_msg)
{
    __shared__ _Float16 st[4][32][136];   // new-state tile (also reused as msg tile)
    __shared__ _Float16 hb[4][32][136];   // MLP hidden tile
    const int lane = threadIdx.x & 63;
    const int wave = threadIdx.x >> 6;
    const int m0 = blockIdx.x * 128 + wave * 32;
    if (m0 >= M) return;
    const int l15 = lane & 15;
    const int kg  = lane >> 4;
    const size_t base = (size_t)m0 * DIM;

    f16x8 xa[2][4], ha[2][4];
    #pragma unroll
    for (int s = 0; s < 2; ++s) {
        const _Float16* xp = X  + base + (size_t)(s * 16 + l15) * DIM + kg * 8;
        const _Float16* hp = Hh + base + (size_t)(s * 16 + l15) * DIM + kg * 8;
        #pragma unroll
        for (int kk = 0; kk < 4; ++kk) {
            xa[s][kk] = *(const f16x8*)(xp + kk * 32);
            ha[s][kk] = *(const f16x8*)(hp + kk * 32);
        }
    }
    for (int jt = 0; jt < 8; ++jt) {
        const int j0 = jt * 16;
        f32x4 ar[2] = {{0,0,0,0},{0,0,0,0}}, az[2] = {{0,0,0,0},{0,0,0,0}};
        f32x4 an[2] = {{0,0,0,0},{0,0,0,0}}, ah[2] = {{0,0,0,0},{0,0,0,0}};
        const _Float16* wi = Wih + (size_t)(j0 + l15) * DIM + kg * 8;
        const _Float16* wh = Whh + (size_t)(j0 + l15) * DIM + kg * 8;
        #pragma unroll
        for (int kk = 0; kk < 4; ++kk) {
            const int o = kk * 32;
            f16x8 wir = *(const f16x8*)(wi + o);
            f16x8 wiz = *(const f16x8*)(wi + 128 * DIM + o);
            f16x8 win = *(const f16x8*)(wi + 256 * DIM + o);
            f16x8 whr = *(const f16x8*)(wh + o);
            f16x8 whz = *(const f16x8*)(wh + 128 * DIM + o);
            f16x8 whn = *(const f16x8*)(wh + 256 * DIM + o);
            #pragma unroll
            for (int s = 0; s < 2; ++s) {
                ar[s] = MFMA16(xa[s][kk], wir, ar[s]);
                ar[s] = MFMA16(ha[s][kk], whr, ar[s]);
                az[s] = MFMA16(xa[s][kk], wiz, az[s]);
                az[s] = MFMA16(ha[s][kk], whz, az[s]);
                an[s] = MFMA16(xa[s][kk], win, an[s]);
                ah[s] = MFMA16(ha[s][kk], whn, ah[s]);
            }
        }
        const int col = j0 + l15;
        float brc = bih[col] + bhh[col];
        float bzc = bih[128 + col] + bhh[128 + col];
        float bgn = bih[256 + col];
        float bhn = bhh[256 + col];
        #pragma unroll
        for (int s = 0; s < 2; ++s)
            #pragma unroll
            for (int r = 0; r < 4; ++r) {
                int row = s * 16 + kg * 4 + r;
                float rg = sigmoidf_(ar[s][r] + brc);
                float zg = sigmoidf_(az[s][r] + bzc);
                float ng = tanhf_(an[s][r] + bgn + rg * (ah[s][r] + bhn));
                float h = (float)Hh[base + (size_t)row * DIM + col];
                st[wave][row][col] = (_Float16)((1.f - zg) * ng + zg * h);
            }
    }
    // coalesced stores from LDS tile
    #pragma unroll
    for (int it = 0; it < 16; ++it) {
        int f = it * 256 + lane * 4;
        f16x4 v = *(const f16x4*)(&st[wave][f >> 7][f & 127]);
        float4 o4 = { (float)v[0], (float)v[1], (float)v[2], (float)v[3] };
        *(float4*)(Hout + base + f) = o4;
    }
    #pragma unroll
    for (int it = 0; it < 8; ++it) {
        int f = it * 512 + lane * 8;
        *(f16x8*)(Hmir + base + f) = *(const f16x8*)(&st[wave][f >> 7][f & 127]);
    }
    if (!do_msg) return;
    // MLP on the new state (tile already in LDS)
    f16x8 a[2][4];
    #pragma unroll
    for (int s = 0; s < 2; ++s)
        #pragma unroll
        for (int kk = 0; kk < 4; ++kk)
            a[s][kk] = *(const f16x8*)(&st[wave][s * 16 + l15][kk * 32 + kg * 8]);
    for (int jt = 0; jt < 8; ++jt) {
        f32x4 acc0 = {0,0,0,0}, acc1 = {0,0,0,0};
        const _Float16* wp = W1 + (size_t)(jt * 16 + l15) * DIM + kg * 8;
        #pragma unroll
        for (int kk = 0; kk < 4; ++kk) {
            f16x8 w = *(const f16x8*)(wp + kk * 32);
            acc0 = MFMA16(a[0][kk], w, acc0);
            acc1 = MFMA16(a[1][kk], w, acc1);
        }
        float bias = B1[jt * 16 + l15];
        #pragma unroll
        for (int r = 0; r < 4; ++r) {
            float v0 = acc0[r] + bias, v1 = acc1[r] + bias;
            hb[wave][kg * 4 + r][jt * 16 + l15]      = (_Float16)(v0 > 0.f ? v0 : 0.f);
            hb[wave][16 + kg * 4 + r][jt * 16 + l15] = (_Float16)(v1 > 0.f ? v1 : 0.f);
        }
    }
    f16x8 h2[2][4];
    #pragma unroll
    for (int s = 0; s < 2; ++s)
        #pragma unroll
        for (int kk = 0; kk < 4; ++kk)
            h2[s][kk] = *(const f16x8*)(&hb[wave][s * 16 + l15][kk * 32 + kg * 8]);
    for (int jt = 0; jt < 8; ++jt) {
        f32x4 acc0 = {0,0,0,0}, acc1 = {0,0,0,0};
        const _Float16* wp = W2 + (size_t)(jt * 16 + l15) * DIM + kg * 8;
        #pragma unroll
        for (int kk = 0; kk < 4; ++kk) {
            f16x8 w = *(const f16x8*)(wp + kk * 32);
            acc0 = MFMA16(h2[0][kk], w, acc0);
            acc1 = MFMA16(h2[1][kk], w, acc1);
        }
        float bias = B2[jt * 16 + l15];
        #pragma unroll
        for (int r = 0; r < 4; ++r) {
            st[wave][kg * 4 + r][jt * 16 + l15]      = (_Float16)(acc0[r] + bias);
            st[wave][16 + kg * 4 + r][jt * 16 + l15] = (_Float16)(acc1[r] + bias);
        }
    }
    #pragma unroll
    for (int it = 0; it < 8; ++it) {
        int f = it * 512 + lane * 8;
        *(f16x8*)(Msg + base + f) = *(const f16x8*)(&st[wave][f >> 7][f & 127]);
    }
}

// literal: x = concat(c2l_aggr, Lh[row^1]), h = Lh[row]. Wih [384,256].
__global__ __launch_bounds__(256) void gru_l_fused(
    const _Float16* __restrict__ X, const _Float16* __restrict__ Lh,
    const _Float16* __restrict__ Wih, const _Float16* __restrict__ Whh,
    const float* __restrict__ bih, const float* __restrict__ bhh,
    float* __restrict__ Lout, _Float16* __restrict__ Lmir,
    const _Float16* __restrict__ W1, const float* __restrict__ B1,
    const _Float16* __restrict__ W2, const float* __restrict__ B2,
    _Float16* __restrict__ Msg, int M, int do_msg)
{
    __shared__ _Float16 st[4][32][136];
    __shared__ _Float16 hb[4][32][136];
    const int lane = threadIdx.x & 63;
    const int wave = threadIdx.x >> 6;
    const int m0 = blockIdx.x * 128 + wave * 32;
    if (m0 >= M) return;
    const int l15 = lane & 15;
    const int kg  = lane >> 4;
    const size_t base = (size_t)m0 * DIM;

    f16x8 xa[2][4], xs[2][4], ha[2][4];
    #pragma unroll
    for (int s = 0; s < 2; ++s) {
        const int row = m0 + s * 16 + l15;
        const _Float16* xp = X  + (size_t)row * DIM + kg * 8;
        const _Float16* sp = Lh + (size_t)(row ^ 1) * DIM + kg * 8;
        const _Float16* hp = Lh + (size_t)row * DIM + kg * 8;
        #pragma unroll
        for (int kk = 0; kk < 4; ++kk) {
            xa[s][kk] = *(const f16x8*)(xp + kk * 32);
            xs[s][kk] = *(const f16x8*)(sp + kk * 32);
            ha[s][kk] = *(const f16x8*)(hp + kk * 32);
        }
    }
    for (int jt = 0; jt < 8; ++jt) {
        const int j0 = jt * 16;
        f32x4 ar[2] = {{0,0,0,0},{0,0,0,0}}, az[2] = {{0,0,0,0},{0,0,0,0}};
        f32x4 an[2] = {{0,0,0,0},{0,0,0,0}}, ah[2] = {{0,0,0,0},{0,0,0,0}};
        const _Float16* wi = Wih + (size_t)(j0 + l15) * 256 + kg * 8;
        const _Float16* wh = Whh + (size_t)(j0 + l15) * DIM + kg * 8;
        #pragma unroll
        for (int kk = 0; kk < 4; ++kk) {
            const int o = kk * 32;
            f16x8 wir = *(const f16x8*)(wi + o);
            f16x8 wiz = *(const f16x8*)(wi + 128 * 256 + o);
            f16x8 win = *(const f16x8*)(wi + 256 * 256 + o);
            f16x8 vir = *(const f16x8*)(wi + 128 + o);
            f16x8 viz = *(const f16x8*)(wi + 128 * 256 + 128 + o);
            f16x8 vin = *(const f16x8*)(wi + 256 * 256 + 128 + o);
            f16x8 whr = *(const f16x8*)(wh + o);
            f16x8 whz = *(const f16x8*)(wh + 128 * DIM + o);
            f16x8 whn = *(const f16x8*)(wh + 256 * DIM + o);
            #pragma unroll
            for (int s = 0; s < 2; ++s) {
                ar[s] = MFMA16(xa[s][kk], wir, ar[s]);
                ar[s] = MFMA16(xs[s][kk], vir, ar[s]);
                ar[s] = MFMA16(ha[s][kk], whr, ar[s]);
                az[s] = MFMA16(xa[s][kk], wiz, az[s]);
                az[s] = MFMA16(xs[s][kk], viz, az[s]);
                az[s] = MFMA16(ha[s][kk], whz, az[s]);
                an[s] = MFMA16(xa[s][kk], win, an[s]);
                an[s] = MFMA16(xs[s][kk], vin, an[s]);
                ah[s] = MFMA16(ha[s][kk], whn, ah[s]);
            }
        }
        const int col = j0 + l15;
        float brc = bih[col] + bhh[col];
        float bzc = bih[128 + col] + bhh[128 + col];
        float bgn = bih[256 + col];
        float bhn = bhh[256 + col];
        #pragma unroll
        for (int s = 0; s < 2; ++s)
            #pragma unroll
            for (int r = 0; r < 4; ++r) {
                int row = s * 16 + kg * 4 + r;
                float rg = sigmoidf_(ar[s][r] + brc);
                float zg = sigmoidf_(az[s][r] + bzc);
                float ng = tanhf_(an[s][r] + bgn + rg * (ah[s][r] + bhn));
                float h = (float)Lh[base + (size_t)row * DIM + col];
                st[wave][row][col] = (_Float16)((1.f - zg) * ng + zg * h);
            }
    }
    #pragma unroll
    for (int it = 0; it < 16; ++it) {
        int f = it * 256 + lane * 4;
        f16x4 v = *(const f16x4*)(&st[wave][f >> 7][f & 127]);
        float4 o4 = { (float)v[0], (float)v[1], (float)v[2], (float)v[3] };
        *(float4*)(Lout + base + f) = o4;
    }
    #pragma unroll
    for (int it = 0; it < 8; ++it) {
        int f = it * 512 + lane * 8;
        *(f16x8*)(Lmir + base + f) = *(const f16x8*)(&st[wave][f >> 7][f & 127]);
    }
    if (!do_msg) return;
    f16x8 a[2][4];
    #pragma unroll
    for (int s = 0; s < 2; ++s)
        #pragma unroll
        for (int kk = 0; kk < 4; ++kk)
            a[s][kk] = *(const f16x8*)(&st[wave][s * 16 + l15][kk * 32 + kg * 8]);
    for (int jt = 0; jt < 8; ++jt) {
        f32x4 acc0 = {0,0,0,0}, acc1 = {0,0,0,0};
        const _Float16* wp = W1 + (size_t)(jt * 16 + l15) * DIM + kg * 8;
        #pragma unroll
        for (int kk = 0; kk < 4; ++kk) {
            f16x8 w = *(const f16x8*)(wp + kk * 32);
            acc0 = MFMA16(a[0][kk], w, acc0);
            acc1 = MFMA16(a[1][kk], w, acc1);
        }
        float bias = B1[jt * 16 + l15];
        #pragma unroll
        for (int r = 0; r < 4; ++r) {
            float v0 = acc0[r] + bias, v1 = acc1[r] + bias;
            hb[wave][kg * 4 + r][jt * 16 + l15]      = (_Float16)(v0 > 0.f ? v0 : 0.f);
            hb[wave][16 + kg * 4 + r][jt * 16 + l15] = (_Float16)(v1 > 0.f ? v1 : 0.f);
        }
    }
    f16x8 h2[2][4];
    #pragma unroll
    for (int s = 0; s < 2; ++s)
        #pragma unroll
        for (int kk = 0; kk < 4; ++kk)
            h2[s][kk] = *(const f16x8*)(&hb[wave][s * 16 + l15][kk * 32 + kg * 8]);
    for (int jt = 0; jt < 8; ++jt) {
        f32x4 acc0 = {0,0,0,0}, acc1 = {0,0,0,0};
        const _Float16* wp = W2 + (size_t)(jt * 16 + l15) * DIM + kg * 8;
        #pragma unroll
        for (int kk = 0; kk < 4; ++kk) {
            f16x8 w = *(const f16x8*)(wp + kk * 32);
            acc0 = MFMA16(h2[0][kk], w, acc0);
            acc1 = MFMA16(h2[1][kk], w, acc1);
        }
        float bias = B2[jt * 16 + l15];
        #pragma unroll
        for (int r = 0; r < 4; ++r) {
            st[wave][kg * 4 + r][jt * 16 + l15]      = (_Float16)(acc0[r] + bias);
            st[wave][16 + kg * 4 + r][jt * 16 + l15] = (_Float16)(acc1[r] + bias);
        }
    }
    #pragma unroll
    for (int it = 0; it < 8; ++it) {
        int f = it * 512 + lane * 8;
        *(f16x8*)(Msg + base + f) = *(const f16x8*)(&st[wave][f >> 7][f & 127]);
    }
}

extern "C" void kernel_launch(void* const* d_in, const int* in_sizes, int n_in,
                              void* d_out, int out_size, void* d_ws, size_t ws_size,
                              hipStream_t stream)
{
    const int*   l_edge = (const int*)d_in[2];
    const int*   c_edge = (const int*)d_in[3];
    const float* l_emb0 = (const float*)d_in[4];
    const float* c_emb0 = (const float*)d_in[5];
    const float* l2c_w1 = (const float*)d_in[6];
    const float* l2c_b1 = (const float*)d_in[7];
    const float* l2c_w2 = (const float*)d_in[8];
    const float* l2c_b2 = (const float*)d_in[9];
    const float* c2l_w1 = (const float*)d_in[10];
    const float* c2l_b1 = (const float*)d_in[11];
    const float* c2l_w2 = (const float*)d_in[12];
    const float* c2l_b2 = (const float*)d_in[13];
    const float* c_w_ih = (const float*)d_in[14];
    const float* c_w_hh = (const float*)d_in[15];
    const float* c_b_ih = (const float*)d_in[16];
    const float* c_b_hh = (const float*)d_in[17];
    const float* l_w_ih = (const float*)d_in[18];
    const float* l_w_hh = (const float*)d_in[19];
    const float* l_b_ih = (const float*)d_in[20];
    const float* l_b_hh = (const float*)d_in[21];

    const int n_edges = in_sizes[2];
    const int Lsz = in_sizes[4] / DIM;   // 80000
    const int Csz = in_sizes[5] / DIM;   // 160000

    float* OUT_L = (float*)d_out;                                  // (5, Lsz, 128)
    float* OUT_C = OUT_L + (size_t)(NITERS + 1) * Lsz * DIM;       // (5, Csz, 128)

    char* wsp = (char*)d_ws;
    auto carve = [&](size_t bytes) -> void* {
        void* p = (void*)wsp;
        wsp += (bytes + 255) & ~(size_t)255;
        return p;
    };
    _Float16* c_msg    = (_Float16*)carve((size_t)Csz * DIM * 2);
    _Float16* l_msg    = (_Float16*)carve((size_t)Lsz * DIM * 2);
    _Float16* l2c_aggr = (_Float16*)carve((size_t)Csz * DIM * 2);
    _Float16* c2l_aggr = (_Float16*)carve((size_t)Lsz * DIM * 2);
    _Float16* Ch0      = (_Float16*)carve((size_t)Csz * DIM * 2);
    _Float16* Ch1      = (_Float16*)carve((size_t)Csz * DIM * 2);
    _Float16* Lh0      = (_Float16*)carve((size_t)Lsz * DIM * 2);
    _Float16* Lh1      = (_Float16*)carve((size_t)Lsz * DIM * 2);
    int* deg_c = (int*)carve((size_t)(Csz)     * 4);
    int* deg_l = (int*)carve((size_t)(Lsz)     * 4);
    int* cur_c = (int*)carve((size_t)(Csz)     * 4);
    int* cur_l = (int*)carve((size_t)(Lsz)     * 4);
    int* rs_c  = (int*)carve((size_t)(Csz + 1) * 4);
    int* rs_l  = (int*)carve((size_t)(Lsz + 1) * 4);
    int* csr_c = (int*)carve((size_t)n_edges   * 4);
    int* csr_l = (int*)carve((size_t)n_edges   * 4);
    int* bsum_c = (int*)carve(256 * 4);
    int* bsum_l = (int*)carve(256 * 4);
    _Float16* hw_l2c1 = (_Float16*)carve((size_t)DIM * DIM * 2);
    _Float16* hw_l2c2 = (_Float16*)carve((size_t)DIM * DIM * 2);
    _Float16* hw_c2l1 = (_Float16*)carve((size_t)DIM * DIM * 2);
    _Float16* hw_c2l2 = (_Float16*)carve((size_t)DIM * DIM * 2);
    _Float16* hw_cih  = (_Float16*)carve((size_t)3 * DIM * DIM * 2);
    _Float16* hw_chh  = (_Float16*)carve((size_t)3 * DIM * DIM * 2);
    _Float16* hw_lih  = (_Float16*)carve((size_t)3 * DIM * 2 * DIM * 2);
    _Float16* hw_lhh  = (_Float16*)carve((size_t)3 * DIM * DIM * 2);

    // all weight conversions in one launch (largest n = 98304 -> 384 blocks)
    {
        ConvDesc cds[8] = {
            { l2c_w1, hw_l2c1, DIM * DIM }, { l2c_w2, hw_l2c2, DIM * DIM },
            { c2l_w1, hw_c2l1, DIM * DIM }, { c2l_w2, hw_c2l2, DIM * DIM },
            { c_w_ih, hw_cih, 3 * DIM * DIM }, { c_w_hh, hw_chh, 3 * DIM * DIM },
            { l_w_ih, hw_lih, 3 * DIM * 2 * DIM }, { l_w_hh, hw_lhh, 3 * DIM * DIM },
        };
        conv8_kernel<<<dim3(384, 8), 256, 0, stream>>>(cds[0], cds[1], cds[2], cds[3],
                                                       cds[4], cds[5], cds[6], cds[7]);
    }

    // initial slices + f16 mirrors
    init_state_kernel<<<(Lsz * DIM / 4 + 255) / 256, 256, 0, stream>>>(l_emb0, OUT_L, Lh0, Lsz * DIM / 4);
    init_state_kernel<<<(Csz * DIM / 4 + 255) / 256, 256, 0, stream>>>(c_emb0, OUT_C, Ch0, Csz * DIM / 4);

    // ---- CSR build (both directions), once per launch ----
    hipMemsetAsync(deg_c, 0, (size_t)Csz * 4, stream);
    hipMemsetAsync(deg_l, 0, (size_t)Lsz * 4, stream);
    hipMemsetAsync(cur_c, 0, (size_t)Csz * 4, stream);
    hipMemsetAsync(cur_l, 0, (size_t)Lsz * 4, stream);

    const int eb = (n_edges + 255) / 256;
    hist_kernel<<<eb, 256, 0, stream>>>(c_edge, deg_c, n_edges);
    hist_kernel<<<eb, 256, 0, stream>>>(l_edge, deg_l, n_edges);

    const int nb_c = (Csz + 1023) / 1024;
    const int nb_l = (Lsz + 1023) / 1024;
    scan_reduce<<<nb_c, 256, 0, stream>>>(deg_c, bsum_c, Csz);
    scan_reduce<<<nb_l, 256, 0, stream>>>(deg_l, bsum_l, Lsz);
    scan_blocksums<<<1, 256, 0, stream>>>(bsum_c, nb_c);
    scan_blocksums<<<1, 256, 0, stream>>>(bsum_l, nb_l);
    scan_write<<<nb_c, 256, 0, stream>>>(deg_c, bsum_c, rs_c, Csz);
    scan_write<<<nb_l, 256, 0, stream>>>(deg_l, bsum_l, rs_l, Lsz);
    set_int_kernel<<<1, 1, 0, stream>>>(rs_c + Csz, n_edges);
    set_int_kernel<<<1, 1, 0, stream>>>(rs_l + Lsz, n_edges);
    fill_kernel<<<eb, 256, 0, stream>>>(l_edge, c_edge, rs_c, cur_c, csr_c, n_edges);
    fill_kernel<<<eb, 256, 0, stream>>>(c_edge, l_edge, rs_l, cur_l, csr_l, n_edges);

    // prologue messages from initial state
    mlp_kernel<<<(Lsz + 127) / 128, 256, 0, stream>>>(Lh0, hw_l2c1, l2c_b1, hw_l2c2, l2c_b2, l_msg, Lsz);
    mlp_kernel<<<(Csz + 127) / 128, 256, 0, stream>>>(Ch0, hw_c2l1, c2l_b1, hw_c2l2, c2l_b2, c_msg, Csz);

    // ---- main loop: gather, gather, fused gru+mlp, fused gru+mlp ----
    for (int t = 0; t < NITERS; ++t) {
        float* Lt1 = OUT_L + (size_t)(t + 1) * Lsz * DIM;
        float* Ct1 = OUT_C + (size_t)(t + 1) * Csz * DIM;
        const _Float16* Lm = (t & 1) ? Lh1 : Lh0;
        const _Float16* Cm = (t & 1) ? Ch1 : Ch0;
        _Float16* Lm1 = (t & 1) ? Lh0 : Lh1;
        _Float16* Cm1 = (t & 1) ? Ch0 : Ch1;
        const int do_msg = (t < NITERS - 1) ? 1 : 0;

        gather_kernel<<<(Csz + 3) / 4, 256, 0, stream>>>(l_msg, rs_c, csr_c, l2c_aggr, Csz);
        gather_kernel<<<(Lsz + 3) / 4, 256, 0, stream>>>(c_msg, rs_l, csr_l, c2l_aggr, Lsz);
        gru_c_fused<<<(Csz + 127) / 128, 256, 0, stream>>>(l2c_aggr, Cm, hw_cih, hw_chh, c_b_ih, c_b_hh,
                                                           Ct1, Cm1, hw_c2l1, c2l_b1, hw_c2l2, c2l_b2,
                                                           c_msg, Csz, do_msg);
        gru_l_fused<<<(Lsz + 127) / 128, 256, 0, stream>>>(c2l_aggr, Lm, hw_lih, hw_lhh, l_b_ih, l_b_hh,
                                                           Lt1, Lm1, hw_l2c1, l2c_b1, hw_l2c2, l2c_b2,
                                                           l_msg, Lsz, do_msg);
    }
}

// Round 5
// 1526.973 us; speedup vs baseline: 5.8450x; 1.2280x over previous
//
#include <hip/hip_runtime.h>

#define DIM 128
#define NITERS 4

typedef _Float16 f16x8 __attribute__((ext_vector_type(8)));
typedef _Float16 f16x4 __attribute__((ext_vector_type(4)));
typedef _Float16 f16x2 __attribute__((ext_vector_type(2)));
typedef float f32x4 __attribute__((ext_vector_type(4)));

#define MFMA16(a, b, c) __builtin_amdgcn_mfma_f32_16x16x32_f16((a), (b), (c), 0, 0, 0)

__device__ __forceinline__ float sigmoidf_(float x) { return 1.f / (1.f + __expf(-x)); }
__device__ __forceinline__ float tanhf_(float x) { return 1.f - 2.f / (__expf(2.f * x) + 1.f); }

struct ConvDesc { const float* s; _Float16* d; int n; };

__global__ __launch_bounds__(256) void conv8_kernel(ConvDesc c0, ConvDesc c1, ConvDesc c2, ConvDesc c3,
                                                    ConvDesc c4, ConvDesc c5, ConvDesc c6, ConvDesc c7) {
    ConvDesc cd;
    switch (blockIdx.y) {
        case 0: cd = c0; break; case 1: cd = c1; break; case 2: cd = c2; break; case 3: cd = c3; break;
        case 4: cd = c4; break; case 5: cd = c5; break; case 6: cd = c6; break; default: cd = c7; break;
    }
    int i = blockIdx.x * 256 + threadIdx.x;
    if (i < cd.n) cd.d[i] = (_Float16)cd.s[i];
}

__global__ __launch_bounds__(256) void init_state_kernel(const float* __restrict__ src,
                                                         float* __restrict__ out32,
                                                         _Float16* __restrict__ out16, int n4) {
    int i = blockIdx.x * 256 + threadIdx.x;
    if (i >= n4) return;
    float4 v = ((const float4*)src)[i];
    ((float4*)out32)[i] = v;
    f16x4 h; h[0] = (_Float16)v.x; h[1] = (_Float16)v.y; h[2] = (_Float16)v.z; h[3] = (_Float16)v.w;
    ((f16x4*)out16)[i] = h;
}

// ---------------- CSR build (once per launch) ----------------

__global__ __launch_bounds__(256) void hist_both(const int* __restrict__ cE, int* __restrict__ degC,
                                                 const int* __restrict__ lE, int* __restrict__ degL,
                                                 int n, int eb) {
    if ((int)blockIdx.x < eb) {
        int i = blockIdx.x * 256 + threadIdx.x;
        if (i < n) atomicAdd(degC + cE[i], 1);
    } else {
        int i = (blockIdx.x - eb) * 256 + threadIdx.x;
        if (i < n) atomicAdd(degL + lE[i], 1);
    }
}

__global__ __launch_bounds__(256) void scan_reduce_both(const int* __restrict__ degC, int* __restrict__ bsC, int nC, int nbC,
                                                        const int* __restrict__ degL, int* __restrict__ bsL, int nL) {
    __shared__ int sh[256];
    const int t = threadIdx.x;
    const int* deg; int* bs; int n, b;
    if ((int)blockIdx.x < nbC) { deg = degC; bs = bsC; n = nC; b = blockIdx.x; }
    else { deg = degL; bs = bsL; n = nL; b = blockIdx.x - nbC; }
    const int base = b * 1024 + t * 4;
    int v = 0;
    #pragma unroll
    for (int k = 0; k < 4; ++k) { int i = base + k; if (i < n) v += deg[i]; }
    sh[t] = v; __syncthreads();
    for (int off = 128; off > 0; off >>= 1) {
        if (t < off) sh[t] += sh[t + off];
        __syncthreads();
    }
    if (t == 0) bs[b] = sh[0];
}

__global__ __launch_bounds__(256) void scan_blocksums_both(int* __restrict__ bsC, int nbC,
                                                           int* __restrict__ bsL, int nbL) {
    __shared__ int sh[256];
    int* bs = blockIdx.x == 0 ? bsC : bsL;
    int nb = blockIdx.x == 0 ? nbC : nbL;
    const int t = threadIdx.x;
    int v = (t < nb) ? bs[t] : 0;
    sh[t] = v; __syncthreads();
    for (int off = 1; off < 256; off <<= 1) {
        int u = (t >= off) ? sh[t - off] : 0;
        __syncthreads();
        sh[t] += u;
        __syncthreads();
    }
    if (t < nb) bs[t] = sh[t] - v;
}

__global__ __launch_bounds__(256) void scan_write_both(const int* __restrict__ degC, const int* __restrict__ bsC,
                                                       int* __restrict__ rsC, int nC, int nbC,
                                                       const int* __restrict__ degL, const int* __restrict__ bsL,
                                                       int* __restrict__ rsL, int nL) {
    __shared__ int sh[256];
    const int t = threadIdx.x;
    const int *deg, *bs; int *rs; int n, b;
    if ((int)blockIdx.x < nbC) { deg = degC; bs = bsC; rs = rsC; n = nC; b = blockIdx.x; }
    else { deg = degL; bs = bsL; rs = rsL; n = nL; b = blockIdx.x - nbC; }
    const int base = b * 1024 + t * 4;
    int v[4], p[4], s = 0;
    #pragma unroll
    for (int k = 0; k < 4; ++k) {
        int i = base + k;
        v[k] = (i < n) ? deg[i] : 0;
        p[k] = s; s += v[k];
    }
    sh[t] = s; __syncthreads();
    for (int off = 1; off < 256; off <<= 1) {
        int u = (t >= off) ? sh[t - off] : 0;
        __syncthreads();
        sh[t] += u;
        __syncthreads();
    }
    int off0 = bs[b] + (sh[t] - s);
    #pragma unroll
    for (int k = 0; k < 4; ++k) {
        int i = base + k;
        if (i < n) rs[i] = off0 + p[k];
    }
}

__global__ void set2_kernel(int* p0, int* p1, int v) { *p0 = v; *p1 = v; }

__global__ __launch_bounds__(256) void fill_both(const int* __restrict__ cE, const int* __restrict__ lE,
                                                 const int* __restrict__ rsC, int* __restrict__ curC, int* __restrict__ csrC,
                                                 const int* __restrict__ rsL, int* __restrict__ curL, int* __restrict__ csrL,
                                                 int n, int eb) {
    if ((int)blockIdx.x < eb) {
        int e = blockIdx.x * 256 + threadIdx.x;
        if (e >= n) return;
        int d = cE[e];
        int slot = atomicAdd(curC + d, 1);
        csrC[rsC[d] + slot] = lE[e];
    } else {
        int e = (blockIdx.x - eb) * 256 + threadIdx.x;
        if (e >= n) return;
        int d = lE[e];
        int slot = atomicAdd(curL + d, 1);
        csrL[rsL[d] + slot] = cE[e];
    }
}

// ---------------- pull-based aggregation (both directions, one dispatch) ----------------
__global__ __launch_bounds__(256) void gather_both(
    const _Float16* __restrict__ msgA, const int* __restrict__ rsA, const int* __restrict__ csrA,
    _Float16* __restrict__ outA, int nA, int blkA,
    const _Float16* __restrict__ msgB, const int* __restrict__ rsB, const int* __restrict__ csrB,
    _Float16* __restrict__ outB, int nB)
{
    const int lane = threadIdx.x & 63;
    const int wave = threadIdx.x >> 6;
    const _Float16* msg; const int *rs, *csr; _Float16* out; int n, d;
    if ((int)blockIdx.x < blkA) { msg = msgA; rs = rsA; csr = csrA; out = outA; n = nA; d = blockIdx.x * 4 + wave; }
    else { msg = msgB; rs = rsB; csr = csrB; out = outB; n = nB; d = (blockIdx.x - blkA) * 4 + wave; }
    if (d >= n) return;
    const int beg = rs[d], end = rs[d + 1];
    float ax = 0.f, ay = 0.f, bx = 0.f, by = 0.f, cx = 0.f, cy = 0.f, dx = 0.f, dy = 0.f;
    int j = beg;
    const int col = lane * 2;
    for (; j + 4 <= end; j += 4) {
        int s0 = csr[j], s1 = csr[j + 1], s2 = csr[j + 2], s3 = csr[j + 3];
        f16x2 v0 = *(const f16x2*)(msg + (size_t)s0 * DIM + col);
        f16x2 v1 = *(const f16x2*)(msg + (size_t)s1 * DIM + col);
        f16x2 v2 = *(const f16x2*)(msg + (size_t)s2 * DIM + col);
        f16x2 v3 = *(const f16x2*)(msg + (size_t)s3 * DIM + col);
        ax += (float)v0[0]; ay += (float)v0[1];
        bx += (float)v1[0]; by += (float)v1[1];
        cx += (float)v2[0]; cy += (float)v2[1];
        dx += (float)v3[0]; dy += (float)v3[1];
    }
    for (; j < end; ++j) {
        int s = csr[j];
        f16x2 v = *(const f16x2*)(msg + (size_t)s * DIM + col);
        ax += (float)v[0]; ay += (float)v[1];
    }
    float ox = (ax + bx) + (cx + dx), oy = (ay + by) + (cy + dy);
    f16x2 o; o[0] = (_Float16)ox; o[1] = (_Float16)oy;
    *(f16x2*)(out + (size_t)d * DIM + col) = o;
}

// ---------------- weight-stationary GRU, both node types, one dispatch ----------------
// 512 threads = 8 waves; wave w owns output cols [16w,16w+16) of every gate; its
// B-fragments (weights) live in VGPRs for the whole kernel. Blocks grid-stride over
// 16-row tiles. No LDS, no barriers.
__global__ __launch_bounds__(512, 2) void gru_both_ws(
    const _Float16* __restrict__ Xc, const _Float16* __restrict__ Chm,
    const _Float16* __restrict__ cWih, const _Float16* __restrict__ cWhh,
    const float* __restrict__ cbih, const float* __restrict__ cbhh,
    float* __restrict__ Cout, _Float16* __restrict__ Cmir, int CTiles, int CBLK,
    const _Float16* __restrict__ Xl, const _Float16* __restrict__ Lhm,
    const _Float16* __restrict__ lWih, const _Float16* __restrict__ lWhh,
    const float* __restrict__ lbih, const float* __restrict__ lbhh,
    float* __restrict__ Lout, _Float16* __restrict__ Lmir, int LTiles)
{
    const int lane = threadIdx.x & 63;
    const int wave = threadIdx.x >> 6;
    const int l15 = lane & 15;
    const int kg  = lane >> 4;
    const int col = wave * 16 + l15;

    if ((int)blockIdx.x < CBLK) {
        // ---- clause GRU: x = l2c_aggr (K=128), h = C mirror ----
        f16x8 wi[3][4], wh[3][4];
        #pragma unroll
        for (int g = 0; g < 3; ++g)
            #pragma unroll
            for (int kk = 0; kk < 4; ++kk) {
                wi[g][kk] = *(const f16x8*)(cWih + (size_t)(g * 128 + col) * DIM + kg * 8 + kk * 32);
                wh[g][kk] = *(const f16x8*)(cWhh + (size_t)(g * 128 + col) * DIM + kg * 8 + kk * 32);
            }
        const float brc = cbih[col] + cbhh[col];
        const float bzc = cbih[128 + col] + cbhh[128 + col];
        const float bgn = cbih[256 + col];
        const float bhn = cbhh[256 + col];
        for (int tile = blockIdx.x; tile < CTiles; tile += CBLK) {
            const size_t r0 = (size_t)tile * 16;
            f16x8 xa[4], ha[4];
            const _Float16* xp = Xc  + (r0 + l15) * DIM + kg * 8;
            const _Float16* hp = Chm + (r0 + l15) * DIM + kg * 8;
            #pragma unroll
            for (int kk = 0; kk < 4; ++kk) {
                xa[kk] = *(const f16x8*)(xp + kk * 32);
                ha[kk] = *(const f16x8*)(hp + kk * 32);
            }
            f32x4 ar = {0,0,0,0}, az = {0,0,0,0}, an = {0,0,0,0}, ah = {0,0,0,0};
            #pragma unroll
            for (int kk = 0; kk < 4; ++kk) {
                ar = MFMA16(xa[kk], wi[0][kk], ar);
                ar = MFMA16(ha[kk], wh[0][kk], ar);
                az = MFMA16(xa[kk], wi[1][kk], az);
                az = MFMA16(ha[kk], wh[1][kk], az);
                an = MFMA16(xa[kk], wi[2][kk], an);
                ah = MFMA16(ha[kk], wh[2][kk], ah);
            }
            #pragma unroll
            for (int r = 0; r < 4; ++r) {
                size_t row = r0 + kg * 4 + r;
                float rg = sigmoidf_(ar[r] + brc);
                float zg = sigmoidf_(az[r] + bzc);
                float ng = tanhf_(an[r] + bgn + rg * (ah[r] + bhn));
                float h = (float)Chm[row * DIM + col];
                float o = (1.f - zg) * ng + zg * h;
                Cout[row * DIM + col] = o;
                Cmir[row * DIM + col] = (_Float16)o;
            }
        }
    } else {
        // ---- literal GRU: x = concat(c2l_aggr, L[row^1]) (K=256), h = L mirror ----
        const int LBLK = gridDim.x - CBLK;
        f16x8 wi[3][8], wh[3][4];
        #pragma unroll
        for (int g = 0; g < 3; ++g) {
            #pragma unroll
            for (int kk = 0; kk < 8; ++kk)
                wi[g][kk] = *(const f16x8*)(lWih + (size_t)(g * 128 + col) * 256 + kg * 8 + kk * 32);
            #pragma unroll
            for (int kk = 0; kk < 4; ++kk)
                wh[g][kk] = *(const f16x8*)(lWhh + (size_t)(g * 128 + col) * DIM + kg * 8 + kk * 32);
        }
        const float brc = lbih[col] + lbhh[col];
        const float bzc = lbih[128 + col] + lbhh[128 + col];
        const float bgn = lbih[256 + col];
        const float bhn = lbhh[256 + col];
        for (int tile = blockIdx.x - CBLK; tile < LTiles; tile += LBLK) {
            const size_t r0 = (size_t)tile * 16;
            f16x8 xa[4], xs[4], ha[4];
            const _Float16* xp = Xl  + (r0 + l15) * DIM + kg * 8;
            const _Float16* hp = Lhm + (r0 + l15) * DIM + kg * 8;
            const _Float16* sp = Lhm + ((r0 + l15) ^ 1) * DIM + kg * 8;
            #pragma unroll
            for (int kk = 0; kk < 4; ++kk) {
                xa[kk] = *(const f16x8*)(xp + kk * 32);
                xs[kk] = *(const f16x8*)(sp + kk * 32);
                ha[kk] = *(const f16x8*)(hp + kk * 32);
            }
            f32x4 ar = {0,0,0,0}, az = {0,0,0,0}, an = {0,0,0,0}, ah = {0,0,0,0};
            #pragma unroll
            for (int kk = 0; kk < 4; ++kk) {
                ar = MFMA16(xa[kk], wi[0][kk],     ar);
                ar = MFMA16(xs[kk], wi[0][kk + 4], ar);
                ar = MFMA16(ha[kk], wh[0][kk],     ar);
                az = MFMA16(xa[kk], wi[1][kk],     az);
                az = MFMA16(xs[kk], wi[1][kk + 4], az);
                az = MFMA16(ha[kk], wh[1][kk],     az);
                an = MFMA16(xa[kk], wi[2][kk],     an);
                an = MFMA16(xs[kk], wi[2][kk + 4], an);
                ah = MFMA16(ha[kk], wh[2][kk],     ah);
            }
            #pragma unroll
            for (int r = 0; r < 4; ++r) {
                size_t row = r0 + kg * 4 + r;
                float rg = sigmoidf_(ar[r] + brc);
                float zg = sigmoidf_(az[r] + bzc);
                float ng = tanhf_(an[r] + bgn + rg * (ah[r] + bhn));
                float h = (float)Lhm[row * DIM + col];
                float o = (1.f - zg) * ng + zg * h;
                Lout[row * DIM + col] = o;
                Lmir[row * DIM + col] = (_Float16)o;
            }
        }
    }
}

// ---------------- weight-stationary message MLP, both node types, one dispatch ----------------
// 512 threads = 8 waves; wave w owns hidden/output cols [16w,16w+16); W1/W2 fragments in VGPRs.
// Hidden tile goes through a double-buffered LDS tile (1 barrier per 16-row tile).
__global__ __launch_bounds__(512, 4) void mlp_both_ws(
    const _Float16* __restrict__ XL, const _Float16* __restrict__ lW1, const float* __restrict__ lB1,
    const _Float16* __restrict__ lW2, const float* __restrict__ lB2, _Float16* __restrict__ MsgL,
    int LTiles, int LBLK,
    const _Float16* __restrict__ XC, const _Float16* __restrict__ cW1, const float* __restrict__ cB1,
    const _Float16* __restrict__ cW2, const float* __restrict__ cB2, _Float16* __restrict__ MsgC,
    int CTiles)
{
    __shared__ _Float16 hid[2][16][136];
    const int lane = threadIdx.x & 63;
    const int wave = threadIdx.x >> 6;
    const int l15 = lane & 15;
    const int kg  = lane >> 4;
    const int col = wave * 16 + l15;

    const _Float16 *X, *W1, *W2; const float *B1p, *B2p; _Float16* Msg;
    int tiles, t0, stride;
    if ((int)blockIdx.x < LBLK) {
        X = XL; W1 = lW1; B1p = lB1; W2 = lW2; B2p = lB2; Msg = MsgL;
        tiles = LTiles; t0 = blockIdx.x; stride = LBLK;
    } else {
        X = XC; W1 = cW1; B1p = cB1; W2 = cW2; B2p = cB2; Msg = MsgC;
        tiles = CTiles; t0 = blockIdx.x - LBLK; stride = gridDim.x - LBLK;
    }
    f16x8 w1[4], w2[4];
    #pragma unroll
    for (int kk = 0; kk < 4; ++kk) {
        w1[kk] = *(const f16x8*)(W1 + (size_t)col * DIM + kg * 8 + kk * 32);
        w2[kk] = *(const f16x8*)(W2 + (size_t)col * DIM + kg * 8 + kk * 32);
    }
    const float b1 = B1p[col], b2 = B2p[col];
    int buf = 0;
    for (int tile = t0; tile < tiles; tile += stride) {
        const size_t r0 = (size_t)tile * 16;
        f16x8 xa[4];
        const _Float16* xp = X + (r0 + l15) * DIM + kg * 8;
        #pragma unroll
        for (int kk = 0; kk < 4; ++kk) xa[kk] = *(const f16x8*)(xp + kk * 32);
        f32x4 a1 = {0,0,0,0};
        #pragma unroll
        for (int kk = 0; kk < 4; ++kk) a1 = MFMA16(xa[kk], w1[kk], a1);
        #pragma unroll
        for (int r = 0; r < 4; ++r) {
            float v = a1[r] + b1;
            hid[buf][kg * 4 + r][col] = (_Float16)(v > 0.f ? v : 0.f);
        }
        __syncthreads();
        f16x8 h2[4];
        #pragma unroll
        for (int kk = 0; kk < 4; ++kk)
            h2[kk] = *(const f16x8*)(&hid[buf][l15][kk * 32 + kg * 8]);
        f32x4 a2 = {0,0,0,0};
        #pragma unroll
        for (int kk = 0; kk < 4; ++kk) a2 = MFMA16(h2[kk], w2[kk], a2);
        #pragma unroll
        for (int r = 0; r < 4; ++r)
            Msg[(r0 + kg * 4 + r) * DIM + col] = (_Float16)(a2[r] + b2);
        buf ^= 1;
    }
}

extern "C" void kernel_launch(void* const* d_in, const int* in_sizes, int n_in,
                              void* d_out, int out_size, void* d_ws, size_t ws_size,
                              hipStream_t stream)
{
    const int*   l_edge = (const int*)d_in[2];
    const int*   c_edge = (const int*)d_in[3];
    const float* l_emb0 = (const float*)d_in[4];
    const float* c_emb0 = (const float*)d_in[5];
    const float* l2c_w1 = (const float*)d_in[6];
    const float* l2c_b1 = (const float*)d_in[7];
    const float* l2c_w2 = (const float*)d_in[8];
    const float* l2c_b2 = (const float*)d_in[9];
    const float* c2l_w1 = (const float*)d_in[10];
    const float* c2l_b1 = (const float*)d_in[11];
    const float* c2l_w2 = (const float*)d_in[12];
    const float* c2l_b2 = (const float*)d_in[13];
    const float* c_w_ih = (const float*)d_in[14];
    const float* c_w_hh = (const float*)d_in[15];
    const float* c_b_ih = (const float*)d_in[16];
    const float* c_b_hh = (const float*)d_in[17];
    const float* l_w_ih = (const float*)d_in[18];
    const float* l_w_hh = (const float*)d_in[19];
    const float* l_b_ih = (const float*)d_in[20];
    const float* l_b_hh = (const float*)d_in[21];

    const int n_edges = in_sizes[2];
    const int Lsz = in_sizes[4] / DIM;   // 80000
    const int Csz = in_sizes[5] / DIM;   // 160000

    float* OUT_L = (float*)d_out;                                  // (5, Lsz, 128)
    float* OUT_C = OUT_L + (size_t)(NITERS + 1) * Lsz * DIM;       // (5, Csz, 128)

    char* wsp = (char*)d_ws;
    auto carve = [&](size_t bytes) -> void* {
        void* p = (void*)wsp;
        wsp += (bytes + 255) & ~(size_t)255;
        return p;
    };
    _Float16* c_msg    = (_Float16*)carve((size_t)Csz * DIM * 2);
    _Float16* l_msg    = (_Float16*)carve((size_t)Lsz * DIM * 2);
    _Float16* l2c_aggr = (_Float16*)carve((size_t)Csz * DIM * 2);
    _Float16* c2l_aggr = (_Float16*)carve((size_t)Lsz * DIM * 2);
    _Float16* Ch0      = (_Float16*)carve((size_t)Csz * DIM * 2);
    _Float16* Ch1      = (_Float16*)carve((size_t)Csz * DIM * 2);
    _Float16* Lh0      = (_Float16*)carve((size_t)Lsz * DIM * 2);
    _Float16* Lh1      = (_Float16*)carve((size_t)Lsz * DIM * 2);
    int* deg_c = (int*)carve((size_t)(Csz)     * 4);   // these four are contiguous:
    int* deg_l = (int*)carve((size_t)(Lsz)     * 4);   // one memset covers them
    int* cur_c = (int*)carve((size_t)(Csz)     * 4);
    int* cur_l = (int*)carve((size_t)(Lsz)     * 4);
    int* rs_c  = (int*)carve((size_t)(Csz + 1) * 4);
    int* rs_l  = (int*)carve((size_t)(Lsz + 1) * 4);
    int* csr_c = (int*)carve((size_t)n_edges   * 4);
    int* csr_l = (int*)carve((size_t)n_edges   * 4);
    int* bsum_c = (int*)carve(256 * 4);
    int* bsum_l = (int*)carve(256 * 4);
    _Float16* hw_l2c1 = (_Float16*)carve((size_t)DIM * DIM * 2);
    _Float16* hw_l2c2 = (_Float16*)carve((size_t)DIM * DIM * 2);
    _Float16* hw_c2l1 = (_Float16*)carve((size_t)DIM * DIM * 2);
    _Float16* hw_c2l2 = (_Float16*)carve((size_t)DIM * DIM * 2);
    _Float16* hw_cih  = (_Float16*)carve((size_t)3 * DIM * DIM * 2);
    _Float16* hw_chh  = (_Float16*)carve((size_t)3 * DIM * DIM * 2);
    _Float16* hw_lih  = (_Float16*)carve((size_t)3 * DIM * 2 * DIM * 2);
    _Float16* hw_lhh  = (_Float16*)carve((size_t)3 * DIM * DIM * 2);

    {
        ConvDesc cds[8] = {
            { l2c_w1, hw_l2c1, DIM * DIM }, { l2c_w2, hw_l2c2, DIM * DIM },
            { c2l_w1, hw_c2l1, DIM * DIM }, { c2l_w2, hw_c2l2, DIM * DIM },
            { c_w_ih, hw_cih, 3 * DIM * DIM }, { c_w_hh, hw_chh, 3 * DIM * DIM },
            { l_w_ih, hw_lih, 3 * DIM * 2 * DIM }, { l_w_hh, hw_lhh, 3 * DIM * DIM },
        };
        conv8_kernel<<<dim3(384, 8), 256, 0, stream>>>(cds[0], cds[1], cds[2], cds[3],
                                                       cds[4], cds[5], cds[6], cds[7]);
    }

    init_state_kernel<<<(Lsz * DIM / 4 + 255) / 256, 256, 0, stream>>>(l_emb0, OUT_L, Lh0, Lsz * DIM / 4);
    init_state_kernel<<<(Csz * DIM / 4 + 255) / 256, 256, 0, stream>>>(c_emb0, OUT_C, Ch0, Csz * DIM / 4);

    // ---- CSR build (both directions) ----
    hipMemsetAsync(deg_c, 0, (size_t)(2 * Csz + 2 * Lsz) * 4, stream);  // deg_c|deg_l|cur_c|cur_l contiguous

    const int eb = (n_edges + 255) / 256;
    hist_both<<<2 * eb, 256, 0, stream>>>(c_edge, deg_c, l_edge, deg_l, n_edges, eb);

    const int nb_c = (Csz + 1023) / 1024;
    const int nb_l = (Lsz + 1023) / 1024;
    scan_reduce_both<<<nb_c + nb_l, 256, 0, stream>>>(deg_c, bsum_c, Csz, nb_c, deg_l, bsum_l, Lsz);
    scan_blocksums_both<<<2, 256, 0, stream>>>(bsum_c, nb_c, bsum_l, nb_l);
    scan_write_both<<<nb_c + nb_l, 256, 0, stream>>>(deg_c, bsum_c, rs_c, Csz, nb_c, deg_l, bsum_l, rs_l, Lsz);
    set2_kernel<<<1, 1, 0, stream>>>(rs_c + Csz, rs_l + Lsz, n_edges);
    fill_both<<<2 * eb, 256, 0, stream>>>(c_edge, l_edge, rs_c, cur_c, csr_c, rs_l, cur_l, csr_l, n_edges, eb);

    const int LTiles = Lsz / 16, CTiles = Csz / 16;
    const int MLP_LBLK = 340, MLP_GRID = 1024;           // 340 L-blocks + 684 C-blocks
    const int GRU_CBLK = 150, GRU_GRID = 256;            // 150 clause + 106 literal blocks
    const int GATH_BLKA = (Csz + 3) / 4;
    const int GATH_GRID = GATH_BLKA + (Lsz + 3) / 4;

    // prologue messages from initial state
    mlp_both_ws<<<MLP_GRID, 512, 0, stream>>>(Lh0, hw_l2c1, l2c_b1, hw_l2c2, l2c_b2, l_msg, LTiles, MLP_LBLK,
                                              Ch0, hw_c2l1, c2l_b1, hw_c2l2, c2l_b2, c_msg, CTiles);

    for (int t = 0; t < NITERS; ++t) {
        float* Lt1 = OUT_L + (size_t)(t + 1) * Lsz * DIM;
        float* Ct1 = OUT_C + (size_t)(t + 1) * Csz * DIM;
        const _Float16* Lm = (t & 1) ? Lh1 : Lh0;
        const _Float16* Cm = (t & 1) ? Ch1 : Ch0;
        _Float16* Lm1 = (t & 1) ? Lh0 : Lh1;
        _Float16* Cm1 = (t & 1) ? Ch0 : Ch1;

        gather_both<<<GATH_GRID, 256, 0, stream>>>(l_msg, rs_c, csr_c, l2c_aggr, Csz, GATH_BLKA,
                                                   c_msg, rs_l, csr_l, c2l_aggr, Lsz);
        gru_both_ws<<<GRU_GRID, 512, 0, stream>>>(l2c_aggr, Cm, hw_cih, hw_chh, c_b_ih, c_b_hh,
                                                  Ct1, Cm1, CTiles, GRU_CBLK,
                                                  c2l_aggr, Lm, hw_lih, hw_lhh, l_b_ih, l_b_hh,
                                                  Lt1, Lm1, LTiles);
        if (t < NITERS - 1)
            mlp_both_ws<<<MLP_GRID, 512, 0, stream>>>(Lm1, hw_l2c1, l2c_b1, hw_l2c2, l2c_b2, l_msg, LTiles, MLP_LBLK,
                                                      Cm1, hw_c2l1, c2l_b1, hw_c2l2, c2l_b2, c_msg, CTiles);
    }
}